// Round 3
// baseline (1626.192 us; speedup 1.0000x reference)
//
#include <hip/hip_runtime.h>

#define DI __device__ __forceinline__

typedef float f32x4 __attribute__((ext_vector_type(4)));
typedef __bf16 bf16x8 __attribute__((ext_vector_type(8)));
typedef __bf16 bf16x4 __attribute__((ext_vector_type(4)));

static DI f32x4 mfma_bf16(bf16x8 a, bf16x8 b, f32x4 c) {
    return __builtin_amdgcn_mfma_f32_16x16x32_bf16(a, b, c, 0, 0, 0);
}
static DI bf16x8 ldb8(const __bf16* p) { return *(const bf16x8*)p; }
static DI float sigf(float x) { return 1.0f / (1.0f + expf(-x)); }

// sc1 coherent (write-through to memory-side cache) stores; relaxed agent atomics.
static DI void stc_u32(void* p, unsigned v) {
    __hip_atomic_store((unsigned*)p, v, __ATOMIC_RELAXED, __HIP_MEMORY_SCOPE_AGENT);
}
static DI unsigned long long ldc_u64(void* p) {
    return __hip_atomic_load((unsigned long long*)p, __ATOMIC_RELAXED, __HIP_MEMORY_SCOPE_AGENT);
}

// B=64, T=32, R=49, LOCAL=1024, QVEC=512, EMB=256, HID=512, VOCAB=10000
#define GRID_BLKS 64

// ---------------- group-local flag barrier (8 blocks per batch-group) ----------------
// Arrival: __syncthreads() drains this block's sc1 data stores to the coherence
// point, then ONE flag store. Wait: 8 lanes poll the group's 8 flags.
static DI void garrive(unsigned* F, int blk, unsigned tgt) {
    __syncthreads();
    if (threadIdx.x == 0)
        __hip_atomic_store(&F[blk], tgt, __ATOMIC_RELAXED, __HIP_MEMORY_SCOPE_AGENT);
}
static DI void gwait(unsigned* F, int base, unsigned tgt) {
    if (threadIdx.x < 64) {
        for (;;) {
            unsigned f = (threadIdx.x < 8)
                ? __hip_atomic_load(&F[base + threadIdx.x], __ATOMIC_RELAXED,
                                    __HIP_MEMORY_SCOPE_AGENT)
                : tgt;
            if (__all(f >= tgt)) break;
            __builtin_amdgcn_s_sleep(1);
        }
    }
    __syncthreads();
}

// ---------------- conversions + gathers (z-dispatched) ----------------
__global__ void convert_kernel(
    const float* Wih, const float* Whh,
    const float* bih, const float* bhh, const float* Wu,
    const float* emb, const int* answers,
    __bf16* WGo, float* biasg, __bf16* WuHo, __bf16* Yo)
{
    int z = blockIdx.z;
    int stride = gridDim.x * blockDim.x;
    int tid0 = blockIdx.x * blockDim.x + threadIdx.x;
    if (z == 0) {
        // Gate-permuted concat [W_ih | W_hh] -> WG [2048 perm rows, 1280]
        // perm row n <-> original row r = (n&3)*512 + (n>>2)  (unit-major)
        const int N = 2048 * 1280;
        for (int i = tid0; i < N; i += stride) {
            int n = i / 1280, k = i - n * 1280;
            int r = (n & 3) * 512 + (n >> 2);
            float val = (k < 768) ? Wih[r * 768 + k] : Whh[r * 512 + (k - 768)];
            WGo[i] = (__bf16)val;
        }
        for (int n = tid0; n < 2048; n += stride) {
            int r = (n & 3) * 512 + (n >> 2);
            biasg[n] = bih[r] + bhh[r];
        }
    } else if (z == 1) {
        // WuH [512 u][512 k] = Wu[u][1024 + k]  (h-part of W_u, original layout)
        const int N = 512 * 512;
        for (int i = tid0; i < N; i += stride) {
            int u = i >> 9, k = i & 511;
            WuHo[i] = (__bf16)Wu[(size_t)u * 1536 + 1024 + k];
        }
    } else {
        // y_seq gather: t=0 -> emb[1]; t>=1 -> emb[answers[b, t-1]]   [32,64,256]
        const int N = 32 * 64 * 256;
        for (int i = tid0; i < N; i += stride) {
            int t = i >> 14;
            int b = (i >> 8) & 63;
            int e = i & 255;
            int tok = (t == 0) ? 1 : answers[b * 32 + (t - 1)];
            Yo[i] = (__bf16)emb[tok * 256 + e];
        }
    }
}

// ---------------- init: h0 = q@Wh^T, c0 = q@Wc^T, o0 = g@Wg2o^T + b ----------------
__global__ void init_kernel(
    const float* q, const float* g,
    const float* Wh, const float* Wc, const float* Wg2o, const float* bg2o,
    __bf16* h0b, float* c0f, __bf16* o0b)
{
    int z = blockIdx.z;
    const float* A; const float* B; int K;
    if (z == 0)      { A = q; B = Wh;   K = 512; }
    else if (z == 1) { A = q; B = Wc;   K = 512; }
    else             { A = g; B = Wg2o; K = 2048; }
    int n0 = blockIdx.x * 64, m0 = blockIdx.y * 16;
    __shared__ float As[32][16];
    __shared__ float Bs[32][64];
    int tid = threadIdx.x;
    int n = tid & 63, tyq = tid >> 6;
    float acc[4] = {0.f, 0.f, 0.f, 0.f};
    for (int k0 = 0; k0 < K; k0 += 32) {
        {
            int idx = tid * 2, row = idx >> 5, kk = idx & 31;
            const float* ar = A + (m0 + row) * K + k0 + kk;
            As[kk][row] = ar[0];
            As[kk + 1][row] = ar[1];
        }
        {
            int row = tid >> 2, kk = (tid & 3) * 8;
            const float* br = B + (n0 + row) * K + k0 + kk;
            float4 v0 = *(const float4*)br;
            float4 v1 = *(const float4*)(br + 4);
            Bs[kk + 0][row] = v0.x; Bs[kk + 1][row] = v0.y;
            Bs[kk + 2][row] = v0.z; Bs[kk + 3][row] = v0.w;
            Bs[kk + 4][row] = v1.x; Bs[kk + 5][row] = v1.y;
            Bs[kk + 6][row] = v1.z; Bs[kk + 7][row] = v1.w;
        }
        __syncthreads();
        #pragma unroll
        for (int k = 0; k < 32; k++) {
            float4 a = *(const float4*)&As[k][tyq * 4];
            float b = Bs[k][n];
            acc[0] += a.x * b; acc[1] += a.y * b; acc[2] += a.z * b; acc[3] += a.w * b;
        }
        __syncthreads();
    }
    int ng = n0 + n;
    #pragma unroll
    for (int i = 0; i < 4; i++) {
        int m = m0 + tyq * 4 + i;
        float v = acc[i];
        if (z == 0)      { h0b[m * 512 + ng] = (__bf16)v; }
        else if (z == 1) { c0f[m * 512 + ng] = v; }
        else             { o0b[m * 512 + ng] = (__bf16)(v + bg2o[ng]); }
    }
}

// ------- proj: out[3136,512] = LF[3136,1024] @ B^T (B rows stride ldb), MFMA -------
// Used twice: AP = LF @ W_attn^T (ldb=1024), LU = LF @ Wu_a^T (ldb=1536, a-part cols).
__global__ __launch_bounds__(256) void attnproj_kernel(
    const float* Af, const float* Bf, int ldb, __bf16* APo)
{
    __shared__ __bf16 As[64][72];
    __shared__ __bf16 Bs[64][72];
    int tid = threadIdx.x;
    int m0 = blockIdx.x * 64, n0 = blockIdx.y * 64;
    int w = tid >> 6, lane = tid & 63, row16 = lane & 15, kg = lane >> 4;
    f32x4 acc[4] = {};
    for (int k0 = 0; k0 < 1024; k0 += 64) {
        int r = tid >> 2, col = (tid & 3) * 16;
        const float* ap = Af + (size_t)(m0 + r) * 1024 + k0 + col;
        const float* bp = Bf + (size_t)(n0 + r) * ldb + k0 + col;
        bf16x8 va0, va1, vb0, vb1;
        #pragma unroll
        for (int u = 0; u < 8; u++) {
            va0[u] = (__bf16)ap[u]; va1[u] = (__bf16)ap[u + 8];
            vb0[u] = (__bf16)bp[u]; vb1[u] = (__bf16)bp[u + 8];
        }
        *(bf16x8*)&As[r][col] = va0; *(bf16x8*)&As[r][col + 8] = va1;
        *(bf16x8*)&Bs[r][col] = vb0; *(bf16x8*)&Bs[r][col + 8] = vb1;
        __syncthreads();
        #pragma unroll
        for (int kt = 0; kt < 2; kt++) {
            bf16x8 af = *(const bf16x8*)&As[w * 16 + row16][kt * 32 + kg * 8];
            #pragma unroll
            for (int j = 0; j < 4; j++) {
                bf16x8 bfv = *(const bf16x8*)&Bs[j * 16 + row16][kt * 32 + kg * 8];
                acc[j] = mfma_bf16(af, bfv, acc[j]);
            }
        }
        __syncthreads();
    }
    #pragma unroll
    for (int j = 0; j < 4; j++)
        #pragma unroll
        for (int r = 0; r < 4; r++)
            APo[(size_t)(m0 + w * 16 + kg * 4 + r) * 512 + n0 + j * 16 + row16] =
                (__bf16)acc[j][r];
}

// ---------------- persistent step-loop kernel (grid = 64 blocks) ----------------
// 2D partition: block blk = (bg = blk>>3, kg = blk&7).
//  Phase A: block computes gates for ITS 8 batches over ITS 64 units (m=8 pad-16
//    MFMA, WG slice kg*256..+256 is XCD-L2-pinned since kg == blk&7 == XCD),
//    LSTM pointwise -> h (sc1 to HS[t+1]), then ChP partial [8b][512u] over its
//    64-k slice of Wu_h via MFMA (64KB LDS-resident weight slice) -> CHP (16KB).
//  Phase BC: block = batch blk: attention (L2-affine AP/LU) + o =
//    tanh(sum_{8 kg} CHP + sum_r att[r]*LU[b][r] + bu) -> OS[t+1].
// The 8 batch-groups are FULLY independent pipelines -> barriers are
// group-local (8 flags), not global. CHP addresses are reused each step ->
// consumers use agent-scope atomic loads (coherence-point-fresh).
__global__ __launch_bounds__(256) void loop_kernel(
    const __bf16* Yall, const __bf16* WG, const float* BG,
    const __bf16* WuH, const float* bu,
    const __bf16* APb, const __bf16* LUb, const float* CF0,
    __bf16* OS, __bf16* HS, float* CHP, unsigned* FLA, unsigned* FLB)
{
    __shared__ float S[8][264];        // gates [8 b][256 n-local]
    __shared__ float Cs[8][64];        // c state [8 b][64 u-local]
    __shared__ __bf16 Hs2[16][72];     // h tile for ChP MFMA (rows 8..15 zero)
    __shared__ __bf16 Bs2[512][72];    // Wu_h slice [512 u][64 k-local]
    __shared__ float BGs[256];         // bias slice
    __shared__ float bus[512];         // bu (full, for BC)
    __shared__ float esh[64];
    __shared__ float ash[64];
    int tid = threadIdx.x;
    int blk = blockIdx.x;
    int bg = blk >> 3, kg = blk & 7;
    int w = tid >> 6, lane = tid & 63, row16 = lane & 15, kg4 = lane >> 4;

    // ---- one-time staging ----
    for (int i = tid; i < 512 * 8; i += 256) {        // Bs2[u][k] <- WuH slice
        int u = i >> 3, c = (i & 7) * 8;
        *(bf16x8*)&Bs2[u][c] = ldb8(WuH + (size_t)u * 512 + kg * 64 + c);
    }
    {
        bf16x8 z = {};
        for (int i = tid; i < 16 * 72 / 8; i += 256) ((bf16x8*)Hs2)[i] = z;
    }
    BGs[tid] = BG[kg * 256 + tid];
    for (int i = tid; i < 512; i += 256) bus[i] = bu[i];
    {   // c0 slice: [8 batches of bg][64 units of kg]
        int b = tid >> 5, ul = (tid & 31) * 2;
        Cs[b][ul]     = CF0[(bg * 8 + b) * 512 + kg * 64 + ul];
        Cs[b][ul + 1] = CF0[(bg * 8 + b) * 512 + kg * 64 + ul + 1];
    }
    __syncthreads();

    for (int t = 0; t < 32; t++) {
        if (t > 0) gwait(FLB, bg * 8, (unsigned)t);   // o(t) of own group ready

        // ---- Phase A ----
        {
            const __bf16* Yt = Yall + t * 16384;
            const __bf16* Op = OS + t * 32768;
            const __bf16* Hp = HS + t * 32768;
            int arow = bg * 8 + (row16 & 7);          // rows 8..15 duplicate 0..7
            int n0 = kg * 256 + w * 64;
            f32x4 acc[4] = {};
            #pragma unroll
            for (int kt = 0; kt < 40; kt++) {
                int k0 = kt * 32;
                bf16x8 af;
                if (k0 < 256)      af = ldb8(Yt + arow * 256 + k0 + kg4 * 8);
                else if (k0 < 768) af = ldb8(Op + arow * 512 + (k0 - 256) + kg4 * 8);
                else               af = ldb8(Hp + arow * 512 + (k0 - 768) + kg4 * 8);
                #pragma unroll
                for (int nt = 0; nt < 4; nt++) {
                    bf16x8 bfv = ldb8(WG + (size_t)(n0 + nt * 16 + row16) * 1280 + k0 + kg4 * 8);
                    acc[nt] = mfma_bf16(af, bfv, acc[nt]);
                }
            }
            if (kg4 < 2) {
                #pragma unroll
                for (int nt = 0; nt < 4; nt++)
                    #pragma unroll
                    for (int r = 0; r < 4; r++)
                        S[kg4 * 4 + r][w * 64 + nt * 16 + row16] = acc[nt][r];
            }
            __syncthreads();
            // pointwise: thread -> (batch-local b, 2 units)
            {
                int b = tid >> 5, ul = (tid & 31) * 2;
                float h2[2];
                #pragma unroll
                for (int uu = 0; uu < 2; uu++) {
                    int u = ul + uu;
                    float gi = S[b][u * 4 + 0] + BGs[u * 4 + 0];
                    float gf = S[b][u * 4 + 1] + BGs[u * 4 + 1];
                    float gg = S[b][u * 4 + 2] + BGs[u * 4 + 2];
                    float go = S[b][u * 4 + 3] + BGs[u * 4 + 3];
                    float cp = Cs[b][u];
                    float cn = sigf(gf) * cp + sigf(gi) * tanhf(gg);
                    h2[uu] = sigf(go) * tanhf(cn);
                    Cs[b][u] = cn;
                }
                Hs2[b][ul] = (__bf16)h2[0];
                Hs2[b][ul + 1] = (__bf16)h2[1];
                union { __bf16 h[2]; unsigned v; } pk;
                pk.h[0] = (__bf16)h2[0]; pk.h[1] = (__bf16)h2[1];
                stc_u32((unsigned*)(HS + (size_t)(t + 1) * 32768 +
                                    (bg * 8 + b) * 512 + kg * 64 + ul), pk.v);
            }
            __syncthreads();
            // ChP partial: [8b (pad 16)][512 u] over k=64, MFMA from LDS
            {
                f32x4 pacc[8] = {};
                #pragma unroll
                for (int kt = 0; kt < 2; kt++) {
                    bf16x8 af = *(const bf16x8*)&Hs2[row16][kt * 32 + kg4 * 8];
                    #pragma unroll
                    for (int nt = 0; nt < 8; nt++) {
                        bf16x8 bv = *(const bf16x8*)&Bs2[w * 128 + nt * 16 + row16][kt * 32 + kg4 * 8];
                        pacc[nt] = mfma_bf16(af, bv, pacc[nt]);
                    }
                }
                if (kg4 < 2) {
                    float* dst = CHP + (size_t)blk * 4096;
                    #pragma unroll
                    for (int nt = 0; nt < 8; nt++) {
                        int u = w * 128 + nt * 16 + row16;
                        #pragma unroll
                        for (int r = 0; r < 4; r++) {
                            union { float f; unsigned v; } c; c.f = pacc[nt][r];
                            stc_u32(dst + (kg4 * 4 + r) * 512 + u, c.v);
                        }
                    }
                }
            }
        }
        garrive(FLA, blk, (unsigned)(t + 1));
        gwait(FLA, bg * 8, (unsigned)(t + 1));

        // ---- Phase BC (block = batch b = blk): attention + o-combine ----
        {
            int b = blk;
            // ChP sum: 8 group producers, L2-bypass 8B loads issued first
            float oh0 = 0.f, oh1 = 0.f;
            {
                float* cp = CHP + (size_t)(bg * 8) * 4096 + (b & 7) * 512 + tid * 2;
                #pragma unroll
                for (int p = 0; p < 8; p++) {
                    union { unsigned long long q; float f[2]; } c;
                    c.q = ldc_u64(cp + p * 4096);
                    oh0 += c.f[0]; oh1 += c.f[1];
                }
            }
            const __bf16* hb = HS + (size_t)(t + 1) * 32768 + b * 512;
            bf16x8 h8 = ldb8(hb + lane * 8);
            // e[r] = attn_proj[b][r] . h
            for (int r = w; r < 49; r += 4) {
                bf16x8 ap8 = ldb8(APb + (size_t)(b * 49 + r) * 512 + lane * 8);
                float s = 0.f;
                #pragma unroll
                for (int u = 0; u < 8; u++) s += (float)ap8[u] * (float)h8[u];
                #pragma unroll
                for (int off = 32; off > 0; off >>= 1) s += __shfl_xor(s, off);
                if (lane == 0) esh[r] = s;
            }
            __syncthreads();
            if (tid < 64) {
                float v = (tid < 49) ? esh[tid] : -3.0e38f;
                float mx = v;
                #pragma unroll
                for (int off = 32; off > 0; off >>= 1) mx = fmaxf(mx, __shfl_xor(mx, off));
                float ex = (tid < 49) ? expf(v - mx) : 0.0f;
                float sm = ex;
                #pragma unroll
                for (int off = 32; off > 0; off >>= 1) sm += __shfl_xor(sm, off);
                if (tid < 49) ash[tid] = ex / sm;
            }
            __syncthreads();
            // a-part via LU: oa[u] = sum_r att[r] * LU[b][r][u]
            float oa0 = 0.f, oa1 = 0.f;
            {
                const __bf16* lu = LUb + (size_t)b * 49 * 512 + tid * 2;
                #pragma unroll 7
                for (int r = 0; r < 49; r++) {
                    float wt = ash[r];
                    union { unsigned u; __bf16 h[2]; } c;
                    c.u = *(const unsigned*)(lu + (size_t)r * 512);
                    oa0 += wt * (float)c.h[0];
                    oa1 += wt * (float)c.h[1];
                }
            }
            int u = tid * 2;
            float o0v = tanhf(oh0 + oa0 + bus[u]);
            float o1v = tanhf(oh1 + oa1 + bus[u + 1]);
            union { __bf16 h[2]; unsigned v; } pk;
            pk.h[0] = (__bf16)o0v; pk.h[1] = (__bf16)o1v;
            stc_u32((unsigned*)(OS + (size_t)(t + 1) * 32768 + b * 512 + u), pk.v);
        }
        garrive(FLB, blk, (unsigned)(t + 1));
    }
}

// ---------------- vocab: logits = O @ Wv^T + b, 128x128 LDS-tiled MFMA ----------------
// B operand converted f32 -> bf16 during LDS staging (no WV buffer needed).
__global__ __launch_bounds__(256) void vocab_kernel(
    const __bf16* A, const float* Wv, const float* bv, float* out)
{
    __shared__ __bf16 As[128][72];
    __shared__ __bf16 Bs[128][72];
    int tid = threadIdx.x;
    int m0 = blockIdx.x * 128;   // 16 mblk
    int n0 = blockIdx.y * 128;   // 79 nblk
    int w = tid >> 6, lane = tid & 63, row16 = lane & 15, kg = lane >> 4;
    int mw = (w & 1) * 64, nw = (w >> 1) * 64;
    f32x4 acc[4][4] = {};
    for (int k0 = 0; k0 < 512; k0 += 64) {
        #pragma unroll
        for (int q = 0; q < 2; q++) {
            int c = q * 256 + tid;
            int r = c >> 2, col = (c & 3) * 16;
            bf16x8 v0 = ldb8(A + (size_t)(m0 + r) * 512 + k0 + col);
            bf16x8 v1 = ldb8(A + (size_t)(m0 + r) * 512 + k0 + col + 8);
            *(bf16x8*)&As[r][col] = v0;
            *(bf16x8*)&As[r][col + 8] = v1;
            bf16x8 u0, u1;
            int nrow = n0 + r;
            if (nrow < 10000) {
                const float* bp = Wv + (size_t)nrow * 512 + k0 + col;
                #pragma unroll
                for (int u = 0; u < 8; u++) {
                    u0[u] = (__bf16)bp[u];
                    u1[u] = (__bf16)bp[u + 8];
                }
            } else {
                u0 = (bf16x8)(__bf16)0.0f;
                u1 = (bf16x8)(__bf16)0.0f;
            }
            *(bf16x8*)&Bs[r][col] = u0;
            *(bf16x8*)&Bs[r][col + 8] = u1;
        }
        __syncthreads();
        #pragma unroll
        for (int kt = 0; kt < 2; kt++) {
            bf16x8 af[4], bfr[4];
            #pragma unroll
            for (int i = 0; i < 4; i++)
                af[i] = *(const bf16x8*)&As[mw + i * 16 + row16][kt * 32 + kg * 8];
            #pragma unroll
            for (int j = 0; j < 4; j++)
                bfr[j] = *(const bf16x8*)&Bs[nw + j * 16 + row16][kt * 32 + kg * 8];
            #pragma unroll
            for (int i = 0; i < 4; i++)
                #pragma unroll
                for (int j = 0; j < 4; j++)
                    acc[i][j] = mfma_bf16(af[i], bfr[j], acc[i][j]);
        }
        __syncthreads();
    }
    #pragma unroll
    for (int j = 0; j < 4; j++) {
        int n = n0 + nw + j * 16 + row16;
        if (n < 10000) {
            float bvn = bv[n];
            #pragma unroll
            for (int i = 0; i < 4; i++) {
                #pragma unroll
                for (int r = 0; r < 4; r++) {
                    int m = m0 + mw + i * 16 + kg * 4 + r;   // m = t*64 + b
                    int tt = m >> 6, b = m & 63;
                    out[(size_t)(b * 32 + tt) * 10000 + n] = acc[i][j][r] + bvn;
                }
            }
        }
    }
}

extern "C" void kernel_launch(void* const* d_in, const int* in_sizes, int n_in,
                              void* d_out, int out_size, void* d_ws, size_t ws_size,
                              hipStream_t stream) {
    (void)in_sizes; (void)n_in; (void)out_size; (void)ws_size;
    const float* localf  = (const float*)d_in[0];
    const float* globalf = (const float*)d_in[1];
    const float* qvec    = (const float*)d_in[2];
    const int*   answers = (const int*)d_in[3];
    const float* emb     = (const float*)d_in[4];
    const float* Wg2o    = (const float*)d_in[5];
    const float* bg2o    = (const float*)d_in[6];
    const float* Wh      = (const float*)d_in[7];
    const float* Wc      = (const float*)d_in[8];
    const float* Wih     = (const float*)d_in[9];
    const float* Whh     = (const float*)d_in[10];
    const float* bih     = (const float*)d_in[11];
    const float* bhh     = (const float*)d_in[12];
    const float* Wattn   = (const float*)d_in[13];
    const float* Wu      = (const float*)d_in[14];
    const float* bu      = (const float*)d_in[15];
    const float* Wvocab  = (const float*)d_in[16];
    const float* bvocab  = (const float*)d_in[17];
    float* out = (float*)d_out;

    char* ws = (char*)d_ws;
    __bf16* WG  = (__bf16*)(ws + 0);          // 2048*1280 bf16 (gate-perm [W_ih|W_hh])   5,242,880
    __bf16* WuH = (__bf16*)(ws + 5242880);    // 512*512 bf16 (Wu h-part, [u][k])           524,288
    __bf16* Y   = (__bf16*)(ws + 5767168);    // 32*64*256 bf16                           1,048,576
    float*  BG  = (float*) (ws + 6815744);    // 2048 f32 (b_ih+b_hh perm)                    8,192
    __bf16* OS  = (__bf16*)(ws + 6823936);    // 33 slots * 64*512 bf16 (o; slot0=o0)     2,162,688
    __bf16* HS  = (__bf16*)(ws + 8986624);    // 33 slots * 64*512 bf16 (h; slot0=h0)     2,162,688
    float*  CF0 = (float*) (ws + 11149312);   // 64*512 f32 (c0)                            131,072
    __bf16* APb = (__bf16*)(ws + 11280384);   // 64*49*512 bf16 (attn_proj)               3,211,264
    __bf16* LUb = (__bf16*)(ws + 14491648);   // 64*49*512 bf16 (LF @ Wu_a^T)             3,211,264
    float*  CHP = (float*) (ws + 17702912);   // 64 blk * 8 b * 512 u f32 (h-part part.)  1,048,576
    unsigned* FLA = (unsigned*)(ws + 18751488); // 64 u32 flags (phase A)                       256
    unsigned* FLB = (unsigned*)(ws + 18751744); // 64 u32 flags (phase BC)                      256
    // total: 18,752,000 B  (within r1-verified >=27.5MB workspace)

    hipMemsetAsync(FLA, 0, 512, stream);
    convert_kernel<<<dim3(1024, 1, 3), 256, 0, stream>>>(
        Wih, Whh, bih, bhh, Wu, emb, answers,
        WG, BG, WuH, Y);
    init_kernel<<<dim3(8, 4, 3), 256, 0, stream>>>(
        qvec, globalf, Wh, Wc, Wg2o, bg2o, HS, CF0, OS);
    attnproj_kernel<<<dim3(49, 8), 256, 0, stream>>>(localf, Wattn, 1024, APb);
    attnproj_kernel<<<dim3(49, 8), 256, 0, stream>>>(localf, Wu, 1536, LUb);
    loop_kernel<<<GRID_BLKS, 256, 0, stream>>>(
        Y, WG, BG, WuH, bu, APb, LUb, CF0, OS, HS, CHP, FLA, FLB);
    vocab_kernel<<<dim3(16, 79), 256, 0, stream>>>(OS + 32768, Wvocab, bvocab, out);
}

// Round 4
// 1155.507 us; speedup vs baseline: 1.4073x; 1.4073x over previous
//
#include <hip/hip_runtime.h>

#define DI __device__ __forceinline__

typedef float f32x4 __attribute__((ext_vector_type(4)));
typedef __bf16 bf16x8 __attribute__((ext_vector_type(8)));
typedef __bf16 bf16x4 __attribute__((ext_vector_type(4)));

static DI f32x4 mfma_bf16(bf16x8 a, bf16x8 b, f32x4 c) {
    return __builtin_amdgcn_mfma_f32_16x16x32_bf16(a, b, c, 0, 0, 0);
}
static DI bf16x8 ldb8(const __bf16* p) { return *(const bf16x8*)p; }
static DI float sigf(float x) { return 1.0f / (1.0f + expf(-x)); }

// sc1 coherent (write-through to memory-side cache) stores; relaxed agent atomics.
static DI void stc_u32(void* p, unsigned v) {
    __hip_atomic_store((unsigned*)p, v, __ATOMIC_RELAXED, __HIP_MEMORY_SCOPE_AGENT);
}
static DI void stc_u64(void* p, unsigned long long v) {
    __hip_atomic_store((unsigned long long*)p, v, __ATOMIC_RELAXED, __HIP_MEMORY_SCOPE_AGENT);
}
static DI unsigned ldc_u32(const void* p) {
    return __hip_atomic_load((const unsigned*)p, __ATOMIC_RELAXED, __HIP_MEMORY_SCOPE_AGENT);
}

// B=64, T=32, R=49, LOCAL=1024, QVEC=512, EMB=256, HID=512, VOCAB=10000
#define GRID_BLKS 64

// ---------------- RMW-free distributed flag barrier ----------------
// Arrival: ONE sc1 store to own flag. Detection: wave 0 polls all 64 flags,
// one per lane. __syncthreads() before the flag store drains this block's sc1
// data stores (vmcnt(0)) so data is at the coherence point before the flag.
static DI void gbar_all(unsigned* FL, int blk, unsigned tgt) {
    __syncthreads();
    if (threadIdx.x < 64) {
        if (threadIdx.x == 0)
            __hip_atomic_store(&FL[blk], tgt, __ATOMIC_RELAXED, __HIP_MEMORY_SCOPE_AGENT);
        for (;;) {
            unsigned f = __hip_atomic_load(&FL[threadIdx.x], __ATOMIC_RELAXED,
                                           __HIP_MEMORY_SCOPE_AGENT);
            if (__all(f >= tgt)) break;
            __builtin_amdgcn_s_sleep(1);
        }
    }
    __syncthreads();
}

// ---------------- conversions + gathers (z-dispatched) ----------------
__global__ void convert_kernel(
    const float* Wih, const float* Whh,
    const float* bih, const float* bhh, const float* Wu,
    const float* emb, const int* answers,
    __bf16* WGo, float* biasg, __bf16* WhTo, __bf16* Yo)
{
    int z = blockIdx.z;
    int stride = gridDim.x * blockDim.x;
    int tid0 = blockIdx.x * blockDim.x + threadIdx.x;
    if (z == 0) {
        // Gate-permuted concat [W_ih | W_hh] -> WG [2048 perm rows, 1280]
        // perm row n <-> original row r = (n&3)*512 + (n>>2)  (unit-major)
        const int N = 2048 * 1280;
        for (int i = tid0; i < N; i += stride) {
            int n = i / 1280, k = i - n * 1280;
            int r = (n & 3) * 512 + (n >> 2);
            float val = (k < 768) ? Wih[r * 768 + k] : Whh[r * 512 + (k - 768)];
            WGo[i] = (__bf16)val;
        }
        for (int n = tid0; n < 2048; n += stride) {
            int r = (n & 3) * 512 + (n >> 2);
            biasg[n] = bih[r] + bhh[r];
        }
    } else if (z == 1) {
        // Wu_hT [512 k][512 u] = Wu[u][1024 + k]  (h-part of W_u, transposed)
        const int N = 512 * 512;
        for (int i = tid0; i < N; i += stride) {
            int k = i >> 9, u = i & 511;
            WhTo[i] = (__bf16)Wu[(size_t)u * 1536 + 1024 + k];
        }
    } else {
        // y_seq gather: t=0 -> emb[1]; t>=1 -> emb[answers[b, t-1]]   [32,64,256]
        const int N = 32 * 64 * 256;
        for (int i = tid0; i < N; i += stride) {
            int t = i >> 14;
            int b = (i >> 8) & 63;
            int e = i & 255;
            int tok = (t == 0) ? 1 : answers[b * 32 + (t - 1)];
            Yo[i] = (__bf16)emb[tok * 256 + e];
        }
    }
}

// ---------------- init: h0 = q@Wh^T, c0 = q@Wc^T, o0 = g@Wg2o^T + b ----------------
__global__ void init_kernel(
    const float* q, const float* g,
    const float* Wh, const float* Wc, const float* Wg2o, const float* bg2o,
    __bf16* h0b, float* c0f, __bf16* o0b)
{
    int z = blockIdx.z;
    const float* A; const float* B; int K;
    if (z == 0)      { A = q; B = Wh;   K = 512; }
    else if (z == 1) { A = q; B = Wc;   K = 512; }
    else             { A = g; B = Wg2o; K = 2048; }
    int n0 = blockIdx.x * 64, m0 = blockIdx.y * 16;
    __shared__ float As[32][16];
    __shared__ float Bs[32][64];
    int tid = threadIdx.x;
    int n = tid & 63, tyq = tid >> 6;
    float acc[4] = {0.f, 0.f, 0.f, 0.f};
    for (int k0 = 0; k0 < K; k0 += 32) {
        {
            int idx = tid * 2, row = idx >> 5, kk = idx & 31;
            const float* ar = A + (m0 + row) * K + k0 + kk;
            As[kk][row] = ar[0];
            As[kk + 1][row] = ar[1];
        }
        {
            int row = tid >> 2, kk = (tid & 3) * 8;
            const float* br = B + (n0 + row) * K + k0 + kk;
            float4 v0 = *(const float4*)br;
            float4 v1 = *(const float4*)(br + 4);
            Bs[kk + 0][row] = v0.x; Bs[kk + 1][row] = v0.y;
            Bs[kk + 2][row] = v0.z; Bs[kk + 3][row] = v0.w;
            Bs[kk + 4][row] = v1.x; Bs[kk + 5][row] = v1.y;
            Bs[kk + 6][row] = v1.z; Bs[kk + 7][row] = v1.w;
        }
        __syncthreads();
        #pragma unroll
        for (int k = 0; k < 32; k++) {
            float4 a = *(const float4*)&As[k][tyq * 4];
            float b = Bs[k][n];
            acc[0] += a.x * b; acc[1] += a.y * b; acc[2] += a.z * b; acc[3] += a.w * b;
        }
        __syncthreads();
    }
    int ng = n0 + n;
    #pragma unroll
    for (int i = 0; i < 4; i++) {
        int m = m0 + tyq * 4 + i;
        float v = acc[i];
        if (z == 0)      { h0b[m * 512 + ng] = (__bf16)v; }
        else if (z == 1) { c0f[m * 512 + ng] = v; }
        else             { o0b[m * 512 + ng] = (__bf16)(v + bg2o[ng]); }
    }
}

// ------- proj: out[3136,512] = LF[3136,1024] @ B^T (B rows stride ldb), MFMA -------
// Used twice: AP = LF @ W_attn^T (ldb=1024), LU = LF @ Wu_a^T (ldb=1536, a-part cols).
__global__ __launch_bounds__(256) void attnproj_kernel(
    const float* Af, const float* Bf, int ldb, __bf16* APo)
{
    __shared__ __bf16 As[64][72];
    __shared__ __bf16 Bs[64][72];
    int tid = threadIdx.x;
    int m0 = blockIdx.x * 64, n0 = blockIdx.y * 64;
    int w = tid >> 6, lane = tid & 63, row16 = lane & 15, kg = lane >> 4;
    f32x4 acc[4] = {};
    for (int k0 = 0; k0 < 1024; k0 += 64) {
        int r = tid >> 2, col = (tid & 3) * 16;
        const float* ap = Af + (size_t)(m0 + r) * 1024 + k0 + col;
        const float* bp = Bf + (size_t)(n0 + r) * ldb + k0 + col;
        bf16x8 va0, va1, vb0, vb1;
        #pragma unroll
        for (int u = 0; u < 8; u++) {
            va0[u] = (__bf16)ap[u]; va1[u] = (__bf16)ap[u + 8];
            vb0[u] = (__bf16)bp[u]; vb1[u] = (__bf16)bp[u + 8];
        }
        *(bf16x8*)&As[r][col] = va0; *(bf16x8*)&As[r][col + 8] = va1;
        *(bf16x8*)&Bs[r][col] = vb0; *(bf16x8*)&Bs[r][col + 8] = vb1;
        __syncthreads();
        #pragma unroll
        for (int kt = 0; kt < 2; kt++) {
            bf16x8 af = *(const bf16x8*)&As[w * 16 + row16][kt * 32 + kg * 8];
            #pragma unroll
            for (int j = 0; j < 4; j++) {
                bf16x8 bfv = *(const bf16x8*)&Bs[j * 16 + row16][kt * 32 + kg * 8];
                acc[j] = mfma_bf16(af, bfv, acc[j]);
            }
        }
        __syncthreads();
    }
    #pragma unroll
    for (int j = 0; j < 4; j++)
        #pragma unroll
        for (int r = 0; r < 4; r++)
            APo[(size_t)(m0 + w * 16 + kg * 4 + r) * 512 + n0 + j * 16 + row16] =
                (__bf16)acc[j][r];
}

// ---------------- persistent step-loop kernel (grid = 64 blocks) ----------------
// r2 1D structure (block = 8-unit slice for phase A, block = batch for BC) with
// latency fixes:
//  - o/h A-operand (cross-block MALL data) preloaded into 32 register quads
//    before the MFMA loop (max MLP; one ~900cy latency instead of ~32 serial).
//  - step-invariant 80KB WG slice staged ONCE into XOR-swizzled LDS
//    (row stride 2560B is bank-aligned; swz byte^=(row&7)<<4 -> 2-way, free).
//  - CHP partials stored bf16 (halved all-to-all traffic).
__global__ __launch_bounds__(256, 1) void loop_kernel(
    const __bf16* Yall, const __bf16* WG, const float* BG,
    const __bf16* WhT, const float* bu,
    const __bf16* APb, const __bf16* LUb, const float* CF0,
    __bf16* OS, __bf16* HS, __bf16* CHP, unsigned* FL)
{
    __shared__ float S[64][33];
    __shared__ float Cs[64][8];
    __shared__ float Hs[64][8];
    __shared__ __bf16 Ws[8][512];      // Wu_hT slice: k in [8*blk, 8*blk+8)
    __shared__ __bf16 WGs[32 * 1280];  // WG slice rows n0..n0+32, XOR-swizzled (80KB)
    __shared__ float BGs[32];
    __shared__ float esh[64];
    __shared__ float ash[64];
    int tid = threadIdx.x;
    int blk = blockIdx.x;
    int w = tid >> 6, lane = tid & 63, row16 = lane & 15, kg4 = lane >> 4;
    int n0 = blk * 32;

    // ---- one-time staging ----
    // WG slice -> LDS, swizzled: 32 rows x 160 granules of 16B
    for (int i = tid; i < 32 * 160; i += 256) {
        int n = i / 160, g = i % 160;
        bf16x8 v = ldb8(WG + (size_t)(n0 + n) * 1280 + g * 8);
        *(bf16x8*)((char*)WGs + ((n * 2560 + g * 16) ^ ((n & 7) << 4))) = v;
    }
    // Wu_hT slice (step-invariant, 8KB)
    for (int i = tid; i < 8 * 512; i += 256)
        Ws[i >> 9][i & 511] = WhT[(size_t)(blk * 8 + (i >> 9)) * 512 + (i & 511)];
    if (tid < 32) BGs[tid] = BG[n0 + tid];
    // c0 slice (units [8*blk, 8*blk+8)) — block-local forever
    {
        int b = tid >> 2, u0 = (tid & 3) * 2;
        Cs[b][u0]     = CF0[b * 512 + blk * 8 + u0];
        Cs[b][u0 + 1] = CF0[b * 512 + blk * 8 + u0 + 1];
    }
    __syncthreads();

    unsigned bgen = 0;
    for (int t = 0; t < 32; t++) {
        // ---- Phase A: gates = [y|o|h] @ WG^T (wave = 16-batch m-tile, full K),
        //      LSTM pointwise -> h (sc1 + LDS), c (LDS), ChP partials (bf16) ----
        {
            const __bf16* Yt = Yall + t * 16384;
            const __bf16* Op = OS + t * 32768;
            const __bf16* Hp = HS + t * 32768;
            int arow = w * 16 + row16;
            // preload MALL-latency o/h A-operand: 32 quads in flight
            bf16x8 a_o[16], a_h[16];
            #pragma unroll
            for (int kt = 0; kt < 16; kt++)
                a_o[kt] = ldb8(Op + arow * 512 + kt * 32 + kg4 * 8);
            #pragma unroll
            for (int kt = 0; kt < 16; kt++)
                a_h[kt] = ldb8(Hp + arow * 512 + kt * 32 + kg4 * 8);
            f32x4 acc[2] = {};
            #pragma unroll
            for (int kt = 0; kt < 40; kt++) {
                bf16x8 af;
                if (kt < 8)       af = ldb8(Yt + arow * 256 + kt * 32 + kg4 * 8);
                else if (kt < 24) af = a_o[kt - 8];
                else              af = a_h[kt - 24];
                #pragma unroll
                for (int nt = 0; nt < 2; nt++) {
                    int row = nt * 16 + row16;
                    bf16x8 bfv = *(const bf16x8*)((const char*)WGs +
                        ((row * 2560 + kt * 64 + kg4 * 16) ^ ((row & 7) << 4)));
                    acc[nt] = mfma_bf16(af, bfv, acc[nt]);
                }
            }
            #pragma unroll
            for (int nt = 0; nt < 2; nt++)
                #pragma unroll
                for (int r = 0; r < 4; r++)
                    S[w * 16 + kg4 * 4 + r][nt * 16 + row16] = acc[nt][r];
            __syncthreads();
            {
                int b = tid >> 2, u0 = (tid & 3) * 2;
                float h2[2];
                #pragma unroll
                for (int uu = 0; uu < 2; uu++) {
                    int u = u0 + uu;
                    float gi = S[b][u * 4 + 0] + BGs[u * 4 + 0];
                    float gf = S[b][u * 4 + 1] + BGs[u * 4 + 1];
                    float gg = S[b][u * 4 + 2] + BGs[u * 4 + 2];
                    float go = S[b][u * 4 + 3] + BGs[u * 4 + 3];
                    float cp = Cs[b][u];
                    float cn = sigf(gf) * cp + sigf(gi) * tanhf(gg);
                    h2[uu] = sigf(go) * tanhf(cn);
                    Cs[b][u] = cn;
                }
                Hs[b][u0] = h2[0];
                Hs[b][u0 + 1] = h2[1];
                union { __bf16 h[2]; unsigned v; } pk;
                pk.h[0] = (__bf16)h2[0]; pk.h[1] = (__bf16)h2[1];
                stc_u32((unsigned*)(HS + (t + 1) * 32768 + b * 512 + blk * 8 + u0), pk.v);
            }
            __syncthreads();
            // ChP[blk][b][u] = sum_{k<8} Hs[b][k] * Ws[k][u]  (bf16 partials)
            {
                int bh = tid >> 7;            // batch half
                int u0 = (tid & 127) * 4;     // 4 units per thread
                #pragma unroll 4
                for (int bb = 0; bb < 32; bb++) {
                    int b = bh * 32 + bb;
                    float a0 = 0.f, a1 = 0.f, a2 = 0.f, a3 = 0.f;
                    #pragma unroll
                    for (int k = 0; k < 8; k++) {
                        float hv = Hs[b][k];
                        bf16x4 wv = *(const bf16x4*)&Ws[k][u0];
                        a0 += hv * (float)wv[0]; a1 += hv * (float)wv[1];
                        a2 += hv * (float)wv[2]; a3 += hv * (float)wv[3];
                    }
                    union { __bf16 h[4]; unsigned long long q; } pk;
                    pk.h[0] = (__bf16)a0; pk.h[1] = (__bf16)a1;
                    pk.h[2] = (__bf16)a2; pk.h[3] = (__bf16)a3;
                    stc_u64(CHP + ((size_t)blk * 64 + b) * 512 + u0, pk.q);
                }
            }
        }
        gbar_all(FL, blk, ++bgen);

        // ---- Phase BC (block = batch b = blk): attention + o-combine ----
        {
            int b = blk;
            const __bf16* hb = HS + (size_t)(t + 1) * 32768 + b * 512;
            bf16x8 h8 = ldb8(hb + lane * 8);
            // ChP sum: 64 independent L2-bypass 4B loads issued early
            float oh0 = 0.f, oh1 = 0.f;
            {
                const __bf16* cp = CHP + (size_t)b * 512 + tid * 2;
                #pragma unroll 16
                for (int p = 0; p < 64; p++) {
                    union { unsigned u; __bf16 h[2]; } c;
                    c.u = ldc_u32(cp + (size_t)p * 32768);
                    oh0 += (float)c.h[0]; oh1 += (float)c.h[1];
                }
            }
            // e[r] = attn_proj[b][r] . h
            for (int r = w; r < 49; r += 4) {
                bf16x8 ap8 = ldb8(APb + (size_t)(b * 49 + r) * 512 + lane * 8);
                float s = 0.f;
                #pragma unroll
                for (int u = 0; u < 8; u++) s += (float)ap8[u] * (float)h8[u];
                #pragma unroll
                for (int off = 32; off > 0; off >>= 1) s += __shfl_xor(s, off);
                if (lane == 0) esh[r] = s;
            }
            __syncthreads();
            if (tid < 64) {
                float v = (tid < 49) ? esh[tid] : -3.0e38f;
                float mx = v;
                #pragma unroll
                for (int off = 32; off > 0; off >>= 1) mx = fmaxf(mx, __shfl_xor(mx, off));
                float ex = (tid < 49) ? expf(v - mx) : 0.0f;
                float sm = ex;
                #pragma unroll
                for (int off = 32; off > 0; off >>= 1) sm += __shfl_xor(sm, off);
                if (tid < 49) ash[tid] = ex / sm;
            }
            __syncthreads();
            // a-part via LU: oa[u] = sum_r att[r] * LU[b][r][u]
            float oa0 = 0.f, oa1 = 0.f;
            {
                const __bf16* lu = LUb + (size_t)b * 49 * 512 + tid * 2;
                #pragma unroll 7
                for (int r = 0; r < 49; r++) {
                    float wt = ash[r];
                    union { unsigned u; __bf16 h[2]; } c;
                    c.u = *(const unsigned*)(lu + (size_t)r * 512);
                    oa0 += wt * (float)c.h[0];
                    oa1 += wt * (float)c.h[1];
                }
            }
            int u = tid * 2;
            float o0v = tanhf(oh0 + oa0 + bu[u]);
            float o1v = tanhf(oh1 + oa1 + bu[u + 1]);
            union { __bf16 h[2]; unsigned v; } pk;
            pk.h[0] = (__bf16)o0v; pk.h[1] = (__bf16)o1v;
            stc_u32((unsigned*)(OS + (size_t)(t + 1) * 32768 + b * 512 + u), pk.v);
        }
        gbar_all(FL, blk, ++bgen);
    }
}

// ---------------- vocab: logits = O @ Wv^T + b, 128x128 LDS-tiled MFMA ----------------
// B operand converted f32 -> bf16 during LDS staging (no WV buffer needed).
__global__ __launch_bounds__(256) void vocab_kernel(
    const __bf16* A, const float* Wv, const float* bv, float* out)
{
    __shared__ __bf16 As[128][72];
    __shared__ __bf16 Bs[128][72];
    int tid = threadIdx.x;
    int m0 = blockIdx.x * 128;   // 16 mblk
    int n0 = blockIdx.y * 128;   // 79 nblk
    int w = tid >> 6, lane = tid & 63, row16 = lane & 15, kg = lane >> 4;
    int mw = (w & 1) * 64, nw = (w >> 1) * 64;
    f32x4 acc[4][4] = {};
    for (int k0 = 0; k0 < 512; k0 += 64) {
        #pragma unroll
        for (int q = 0; q < 2; q++) {
            int c = q * 256 + tid;
            int r = c >> 2, col = (c & 3) * 16;
            bf16x8 v0 = ldb8(A + (size_t)(m0 + r) * 512 + k0 + col);
            bf16x8 v1 = ldb8(A + (size_t)(m0 + r) * 512 + k0 + col + 8);
            *(bf16x8*)&As[r][col] = v0;
            *(bf16x8*)&As[r][col + 8] = v1;
            bf16x8 u0, u1;
            int nrow = n0 + r;
            if (nrow < 10000) {
                const float* bp = Wv + (size_t)nrow * 512 + k0 + col;
                #pragma unroll
                for (int u = 0; u < 8; u++) {
                    u0[u] = (__bf16)bp[u];
                    u1[u] = (__bf16)bp[u + 8];
                }
            } else {
                u0 = (bf16x8)(__bf16)0.0f;
                u1 = (bf16x8)(__bf16)0.0f;
            }
            *(bf16x8*)&Bs[r][col] = u0;
            *(bf16x8*)&Bs[r][col + 8] = u1;
        }
        __syncthreads();
        #pragma unroll
        for (int kt = 0; kt < 2; kt++) {
            bf16x8 af[4], bfr[4];
            #pragma unroll
            for (int i = 0; i < 4; i++)
                af[i] = *(const bf16x8*)&As[mw + i * 16 + row16][kt * 32 + kg * 8];
            #pragma unroll
            for (int j = 0; j < 4; j++)
                bfr[j] = *(const bf16x8*)&Bs[nw + j * 16 + row16][kt * 32 + kg * 8];
            #pragma unroll
            for (int i = 0; i < 4; i++)
                #pragma unroll
                for (int j = 0; j < 4; j++)
                    acc[i][j] = mfma_bf16(af[i], bfr[j], acc[i][j]);
        }
        __syncthreads();
    }
    #pragma unroll
    for (int j = 0; j < 4; j++) {
        int n = n0 + nw + j * 16 + row16;
        if (n < 10000) {
            float bvn = bv[n];
            #pragma unroll
            for (int i = 0; i < 4; i++) {
                #pragma unroll
                for (int r = 0; r < 4; r++) {
                    int m = m0 + mw + i * 16 + kg * 4 + r;   // m = t*64 + b
                    int tt = m >> 6, b = m & 63;
                    out[(size_t)(b * 32 + tt) * 10000 + n] = acc[i][j][r] + bvn;
                }
            }
        }
    }
}

extern "C" void kernel_launch(void* const* d_in, const int* in_sizes, int n_in,
                              void* d_out, int out_size, void* d_ws, size_t ws_size,
                              hipStream_t stream) {
    (void)in_sizes; (void)n_in; (void)out_size; (void)ws_size;
    const float* localf  = (const float*)d_in[0];
    const float* globalf = (const float*)d_in[1];
    const float* qvec    = (const float*)d_in[2];
    const int*   answers = (const int*)d_in[3];
    const float* emb     = (const float*)d_in[4];
    const float* Wg2o    = (const float*)d_in[5];
    const float* bg2o    = (const float*)d_in[6];
    const float* Wh      = (const float*)d_in[7];
    const float* Wc      = (const float*)d_in[8];
    const float* Wih     = (const float*)d_in[9];
    const float* Whh     = (const float*)d_in[10];
    const float* bih     = (const float*)d_in[11];
    const float* bhh     = (const float*)d_in[12];
    const float* Wattn   = (const float*)d_in[13];
    const float* Wu      = (const float*)d_in[14];
    const float* bu      = (const float*)d_in[15];
    const float* Wvocab  = (const float*)d_in[16];
    const float* bvocab  = (const float*)d_in[17];
    float* out = (float*)d_out;

    char* ws = (char*)d_ws;
    __bf16* WG  = (__bf16*)(ws + 0);          // 2048*1280 bf16 (gate-perm [W_ih|W_hh])   5,242,880
    __bf16* WhT = (__bf16*)(ws + 5242880);    // 512*512 bf16 (Wu_h transposed)             524,288
    __bf16* Y   = (__bf16*)(ws + 5767168);    // 32*64*256 bf16                           1,048,576
    float*  BG  = (float*) (ws + 6815744);    // 2048 f32 (b_ih+b_hh perm)                    8,192
    __bf16* OS  = (__bf16*)(ws + 6823936);    // 33 slots * 64*512 bf16 (o; slot0=o0)     2,162,688
    __bf16* HS  = (__bf16*)(ws + 8986624);    // 33 slots * 64*512 bf16 (h; slot0=h0)     2,162,688
    float*  CF0 = (float*) (ws + 11149312);   // 64*512 f32 (c0)                            131,072
    __bf16* APb = (__bf16*)(ws + 11280384);   // 64*49*512 bf16 (attn_proj)               3,211,264
    __bf16* LUb = (__bf16*)(ws + 14491648);   // 64*49*512 bf16 (LF @ Wu_a^T)             3,211,264
    __bf16* CHP = (__bf16*)(ws + 17702912);   // 64 blk * 64 b * 512 u bf16 (h-part)      4,194,304
    unsigned* FL = (unsigned*)(ws + 21897216); // 64 u32 flags                                 256
    // total: 21,897,472 B  (within r1-verified >=27.5MB workspace)

    hipMemsetAsync(FL, 0, 256, stream);
    convert_kernel<<<dim3(1024, 1, 3), 256, 0, stream>>>(
        Wih, Whh, bih, bhh, Wu, emb, answers,
        WG, BG, WhT, Y);
    init_kernel<<<dim3(8, 4, 3), 256, 0, stream>>>(
        qvec, globalf, Wh, Wc, Wg2o, bg2o, HS, CF0, OS);
    attnproj_kernel<<<dim3(49, 8), 256, 0, stream>>>(localf, Wattn, 1024, APb);
    attnproj_kernel<<<dim3(49, 8), 256, 0, stream>>>(localf, Wu, 1536, LUb);
    loop_kernel<<<GRID_BLKS, 256, 0, stream>>>(
        Y, WG, BG, WhT, bu, APb, LUb, CF0, OS, HS, CHP, FL);
    vocab_kernel<<<dim3(16, 79), 256, 0, stream>>>(OS + 32768, Wvocab, bvocab, out);
}

// Round 5
// 1123.047 us; speedup vs baseline: 1.4480x; 1.0289x over previous
//
#include <hip/hip_runtime.h>

#define DI __device__ __forceinline__

typedef float f32x4 __attribute__((ext_vector_type(4)));
typedef __bf16 bf16x8 __attribute__((ext_vector_type(8)));
typedef __bf16 bf16x4 __attribute__((ext_vector_type(4)));

static DI f32x4 mfma_bf16(bf16x8 a, bf16x8 b, f32x4 c) {
    return __builtin_amdgcn_mfma_f32_16x16x32_bf16(a, b, c, 0, 0, 0);
}
static DI bf16x8 ldb8(const __bf16* p) { return *(const bf16x8*)p; }
static DI float sigf(float x) { return 1.0f / (1.0f + expf(-x)); }

// sc1 coherent (write-through to memory-side cache) stores; relaxed agent atomics.
static DI void stc_u32(void* p, unsigned v) {
    __hip_atomic_store((unsigned*)p, v, __ATOMIC_RELAXED, __HIP_MEMORY_SCOPE_AGENT);
}
static DI void stc_u64(void* p, unsigned long long v) {
    __hip_atomic_store((unsigned long long*)p, v, __ATOMIC_RELAXED, __HIP_MEMORY_SCOPE_AGENT);
}
static DI unsigned ldc_u32(const void* p) {
    return __hip_atomic_load((const unsigned*)p, __ATOMIC_RELAXED, __HIP_MEMORY_SCOPE_AGENT);
}

// B=64, T=32, R=49, LOCAL=1024, QVEC=512, EMB=256, HID=512, VOCAB=10000
#define GRID_BLKS 64

// ---------------- RMW-free distributed flag barrier (split arrive/wait) ----------------
// Arrival: __syncthreads() drains this block's sc1 data stores (vmcnt(0)) so data
// is at the coherence point before the flag becomes visible; then ONE flag store.
// Wait: wave 0 polls all 64 flags, one per lane.
static DI void garrive(unsigned* F, int blk, unsigned tgt) {
    __syncthreads();
    if (threadIdx.x == 0)
        __hip_atomic_store(&F[blk], tgt, __ATOMIC_RELAXED, __HIP_MEMORY_SCOPE_AGENT);
}
static DI void gwait_all(unsigned* F, unsigned tgt) {
    if (threadIdx.x < 64) {
        for (;;) {
            unsigned f = __hip_atomic_load(&F[threadIdx.x], __ATOMIC_RELAXED,
                                           __HIP_MEMORY_SCOPE_AGENT);
            if (__all(f >= tgt)) break;
            __builtin_amdgcn_s_sleep(1);
        }
    }
    __syncthreads();
}

// ---------------- conversions + gathers (z-dispatched) ----------------
__global__ void convert_kernel(
    const float* Wih, const float* Whh,
    const float* bih, const float* bhh, const float* Wu,
    const float* emb, const int* answers,
    __bf16* WGo, float* biasg, __bf16* WhTo, __bf16* Yo)
{
    int z = blockIdx.z;
    int stride = gridDim.x * blockDim.x;
    int tid0 = blockIdx.x * blockDim.x + threadIdx.x;
    if (z == 0) {
        // Gate-permuted concat [W_ih | W_hh] -> WG [2048 perm rows, 1280]
        // perm row n <-> original row r = (n&3)*512 + (n>>2)  (unit-major)
        const int N = 2048 * 1280;
        for (int i = tid0; i < N; i += stride) {
            int n = i / 1280, k = i - n * 1280;
            int r = (n & 3) * 512 + (n >> 2);
            float val = (k < 768) ? Wih[r * 768 + k] : Whh[r * 512 + (k - 768)];
            WGo[i] = (__bf16)val;
        }
        for (int n = tid0; n < 2048; n += stride) {
            int r = (n & 3) * 512 + (n >> 2);
            biasg[n] = bih[r] + bhh[r];
        }
    } else if (z == 1) {
        // Wu_hT [512 k][512 u] = Wu[u][1024 + k]  (h-part of W_u, transposed)
        const int N = 512 * 512;
        for (int i = tid0; i < N; i += stride) {
            int k = i >> 9, u = i & 511;
            WhTo[i] = (__bf16)Wu[(size_t)u * 1536 + 1024 + k];
        }
    } else {
        // y_seq gather: t=0 -> emb[1]; t>=1 -> emb[answers[b, t-1]]   [32,64,256]
        const int N = 32 * 64 * 256;
        for (int i = tid0; i < N; i += stride) {
            int t = i >> 14;
            int b = (i >> 8) & 63;
            int e = i & 255;
            int tok = (t == 0) ? 1 : answers[b * 32 + (t - 1)];
            Yo[i] = (__bf16)emb[tok * 256 + e];
        }
    }
}

// ---------------- init: h0 = q@Wh^T, c0 = q@Wc^T, o0 = g@Wg2o^T + b ----------------
__global__ void init_kernel(
    const float* q, const float* g,
    const float* Wh, const float* Wc, const float* Wg2o, const float* bg2o,
    __bf16* h0b, float* c0f, __bf16* o0b)
{
    int z = blockIdx.z;
    const float* A; const float* B; int K;
    if (z == 0)      { A = q; B = Wh;   K = 512; }
    else if (z == 1) { A = q; B = Wc;   K = 512; }
    else             { A = g; B = Wg2o; K = 2048; }
    int n0 = blockIdx.x * 64, m0 = blockIdx.y * 16;
    __shared__ float As[32][16];
    __shared__ float Bs[32][64];
    int tid = threadIdx.x;
    int n = tid & 63, tyq = tid >> 6;
    float acc[4] = {0.f, 0.f, 0.f, 0.f};
    for (int k0 = 0; k0 < K; k0 += 32) {
        {
            int idx = tid * 2, row = idx >> 5, kk = idx & 31;
            const float* ar = A + (m0 + row) * K + k0 + kk;
            As[kk][row] = ar[0];
            As[kk + 1][row] = ar[1];
        }
        {
            int row = tid >> 2, kk = (tid & 3) * 8;
            const float* br = B + (n0 + row) * K + k0 + kk;
            float4 v0 = *(const float4*)br;
            float4 v1 = *(const float4*)(br + 4);
            Bs[kk + 0][row] = v0.x; Bs[kk + 1][row] = v0.y;
            Bs[kk + 2][row] = v0.z; Bs[kk + 3][row] = v0.w;
            Bs[kk + 4][row] = v1.x; Bs[kk + 5][row] = v1.y;
            Bs[kk + 6][row] = v1.z; Bs[kk + 7][row] = v1.w;
        }
        __syncthreads();
        #pragma unroll
        for (int k = 0; k < 32; k++) {
            float4 a = *(const float4*)&As[k][tyq * 4];
            float b = Bs[k][n];
            acc[0] += a.x * b; acc[1] += a.y * b; acc[2] += a.z * b; acc[3] += a.w * b;
        }
        __syncthreads();
    }
    int ng = n0 + n;
    #pragma unroll
    for (int i = 0; i < 4; i++) {
        int m = m0 + tyq * 4 + i;
        float v = acc[i];
        if (z == 0)      { h0b[m * 512 + ng] = (__bf16)v; }
        else if (z == 1) { c0f[m * 512 + ng] = v; }
        else             { o0b[m * 512 + ng] = (__bf16)(v + bg2o[ng]); }
    }
}

// ------- proj: out[3136,512] = LF[3136,1024] @ B^T (B rows stride ldb), MFMA -------
// Used twice: AP = LF @ W_attn^T (ldb=1024), LU = LF @ Wu_a^T (ldb=1536, a-part cols).
__global__ __launch_bounds__(256) void attnproj_kernel(
    const float* Af, const float* Bf, int ldb, __bf16* APo)
{
    __shared__ __bf16 As[64][72];
    __shared__ __bf16 Bs[64][72];
    int tid = threadIdx.x;
    int m0 = blockIdx.x * 64, n0 = blockIdx.y * 64;
    int w = tid >> 6, lane = tid & 63, row16 = lane & 15, kg = lane >> 4;
    f32x4 acc[4] = {};
    for (int k0 = 0; k0 < 1024; k0 += 64) {
        int r = tid >> 2, col = (tid & 3) * 16;
        const float* ap = Af + (size_t)(m0 + r) * 1024 + k0 + col;
        const float* bp = Bf + (size_t)(n0 + r) * ldb + k0 + col;
        bf16x8 va0, va1, vb0, vb1;
        #pragma unroll
        for (int u = 0; u < 8; u++) {
            va0[u] = (__bf16)ap[u]; va1[u] = (__bf16)ap[u + 8];
            vb0[u] = (__bf16)bp[u]; vb1[u] = (__bf16)bp[u + 8];
        }
        *(bf16x8*)&As[r][col] = va0; *(bf16x8*)&As[r][col + 8] = va1;
        *(bf16x8*)&Bs[r][col] = vb0; *(bf16x8*)&Bs[r][col + 8] = vb1;
        __syncthreads();
        #pragma unroll
        for (int kt = 0; kt < 2; kt++) {
            bf16x8 af = *(const bf16x8*)&As[w * 16 + row16][kt * 32 + kg * 8];
            #pragma unroll
            for (int j = 0; j < 4; j++) {
                bf16x8 bfv = *(const bf16x8*)&Bs[j * 16 + row16][kt * 32 + kg * 8];
                acc[j] = mfma_bf16(af, bfv, acc[j]);
            }
        }
        __syncthreads();
    }
    #pragma unroll
    for (int j = 0; j < 4; j++)
        #pragma unroll
        for (int r = 0; r < 4; r++)
            APo[(size_t)(m0 + w * 16 + kg * 4 + r) * 512 + n0 + j * 16 + row16] =
                (__bf16)acc[j][r];
}

// ---------------- persistent step-loop kernel (grid = 64 blocks) ----------------
// r4 structure + latency fixes:
//  - compiler memory barriers pin the o/h A-operand preloads BEFORE the MFMA
//    loop (r4's VGPR=132 showed the compiler sank them in-loop -> serialized
//    ~900cy MALL latencies; this was the dominant per-step cost).
//  - o-independent gate part (y + h, 24/40 kt) hoisted ABOVE the FLB wait:
//    overlaps other blocks' BC phase. Requires CHP parity double-buffer
//    (run-ahead skew is bounded at 1 phase by the FLB wait).
//  - BC ChP-sum: all 64 agent-scope loads issued as one register batch.
//  - S stride 33->34 (4-way epilogue bank conflict -> 2-way = free).
__global__ __launch_bounds__(256, 1) void loop_kernel(
    const __bf16* Yall, const __bf16* WG, const float* BG,
    const __bf16* WhT, const float* bu,
    const __bf16* APb, const __bf16* LUb, const float* CF0,
    __bf16* OS, __bf16* HS, __bf16* CHP, unsigned* FLA, unsigned* FLB)
{
    __shared__ float S[64][34];
    __shared__ float Cs[64][8];
    __shared__ float Hs[64][8];
    __shared__ __bf16 Ws[8][512];      // Wu_hT slice: k in [8*blk, 8*blk+8)
    __shared__ __bf16 WGs[32 * 1280];  // WG slice rows n0..n0+32, XOR-swizzled (80KB)
    __shared__ float BGs[32];
    __shared__ float esh[64];
    __shared__ float ash[64];
    int tid = threadIdx.x;
    int blk = blockIdx.x;
    int w = tid >> 6, lane = tid & 63, row16 = lane & 15, kg4 = lane >> 4;
    int n0 = blk * 32;

    // ---- one-time staging ----
    // WG slice -> LDS, swizzled: 32 rows x 160 granules of 16B
    for (int i = tid; i < 32 * 160; i += 256) {
        int n = i / 160, g = i % 160;
        bf16x8 v = ldb8(WG + (size_t)(n0 + n) * 1280 + g * 8);
        *(bf16x8*)((char*)WGs + ((n * 2560 + g * 16) ^ ((n & 7) << 4))) = v;
    }
    // Wu_hT slice (step-invariant, 8KB)
    for (int i = tid; i < 8 * 512; i += 256)
        Ws[i >> 9][i & 511] = WhT[(size_t)(blk * 8 + (i >> 9)) * 512 + (i & 511)];
    if (tid < 32) BGs[tid] = BG[n0 + tid];
    // c0 slice (units [8*blk, 8*blk+8)) — block-local forever
    {
        int b = tid >> 2, u0 = (tid & 3) * 2;
        Cs[b][u0]     = CF0[b * 512 + blk * 8 + u0];
        Cs[b][u0 + 1] = CF0[b * 512 + blk * 8 + u0 + 1];
    }
    __syncthreads();
    // step-invariant Ws fragment for the ChP partial (4 units x 8 k per thread)
    float wreg[8][4];
    {
        int u0c = (tid & 127) * 4;
        #pragma unroll
        for (int k = 0; k < 8; k++)
            #pragma unroll
            for (int j = 0; j < 4; j++)
                wreg[k][j] = (float)Ws[k][u0c + j];
    }

    for (int t = 0; t < 32; t++) {
        int arow = w * 16 + row16;
        f32x4 acc[2] = {};
        // ---- segment 1 (o-independent, overlaps other blocks' BC):
        //      h-preload + y-part (kt 0..7) + h-part (kt 24..39) ----
        {
            const __bf16* Yt = Yall + t * 16384;
            const __bf16* Hp = HS + t * 32768;
            bf16x8 a_h[16];
            #pragma unroll
            for (int kt = 0; kt < 16; kt++)
                a_h[kt] = ldb8(Hp + arow * 512 + kt * 32 + kg4 * 8);
            asm volatile("" ::: "memory");   // pin preloads: 16 loads in flight
            #pragma unroll
            for (int kt = 0; kt < 8; kt++) {
                bf16x8 af = ldb8(Yt + arow * 256 + kt * 32 + kg4 * 8);
                #pragma unroll
                for (int nt = 0; nt < 2; nt++) {
                    int row = nt * 16 + row16;
                    bf16x8 bfv = *(const bf16x8*)((const char*)WGs +
                        ((row * 2560 + kt * 64 + kg4 * 16) ^ ((row & 7) << 4)));
                    acc[nt] = mfma_bf16(af, bfv, acc[nt]);
                }
            }
            #pragma unroll
            for (int kt = 24; kt < 40; kt++) {
                bf16x8 af = a_h[kt - 24];
                #pragma unroll
                for (int nt = 0; nt < 2; nt++) {
                    int row = nt * 16 + row16;
                    bf16x8 bfv = *(const bf16x8*)((const char*)WGs +
                        ((row * 2560 + kt * 64 + kg4 * 16) ^ ((row & 7) << 4)));
                    acc[nt] = mfma_bf16(af, bfv, acc[nt]);
                }
            }
        }
        gwait_all(FLB, (unsigned)t);   // o(t) visible (trivially true at t=0)

        // ---- segment 2: o-part (kt 8..23), pointwise, ChP ----
        {
            const __bf16* Op = OS + t * 32768;
            bf16x8 a_o[16];
            #pragma unroll
            for (int kt = 0; kt < 16; kt++)
                a_o[kt] = ldb8(Op + arow * 512 + kt * 32 + kg4 * 8);
            asm volatile("" ::: "memory");   // pin preloads
            #pragma unroll
            for (int kt = 8; kt < 24; kt++) {
                bf16x8 af = a_o[kt - 8];
                #pragma unroll
                for (int nt = 0; nt < 2; nt++) {
                    int row = nt * 16 + row16;
                    bf16x8 bfv = *(const bf16x8*)((const char*)WGs +
                        ((row * 2560 + kt * 64 + kg4 * 16) ^ ((row & 7) << 4)));
                    acc[nt] = mfma_bf16(af, bfv, acc[nt]);
                }
            }
            #pragma unroll
            for (int nt = 0; nt < 2; nt++)
                #pragma unroll
                for (int r = 0; r < 4; r++)
                    S[w * 16 + kg4 * 4 + r][nt * 16 + row16] = acc[nt][r];
            __syncthreads();
            {
                int b = tid >> 2, u0 = (tid & 3) * 2;
                float h2[2];
                #pragma unroll
                for (int uu = 0; uu < 2; uu++) {
                    int u = u0 + uu;
                    float gi = S[b][u * 4 + 0] + BGs[u * 4 + 0];
                    float gf = S[b][u * 4 + 1] + BGs[u * 4 + 1];
                    float gg = S[b][u * 4 + 2] + BGs[u * 4 + 2];
                    float go = S[b][u * 4 + 3] + BGs[u * 4 + 3];
                    float cp = Cs[b][u];
                    float cn = sigf(gf) * cp + sigf(gi) * tanhf(gg);
                    h2[uu] = sigf(go) * tanhf(cn);
                    Cs[b][u] = cn;
                }
                Hs[b][u0] = h2[0];
                Hs[b][u0 + 1] = h2[1];
                union { __bf16 h[2]; unsigned v; } pk;
                pk.h[0] = (__bf16)h2[0]; pk.h[1] = (__bf16)h2[1];
                stc_u32((unsigned*)(HS + (t + 1) * 32768 + b * 512 + blk * 8 + u0), pk.v);
            }
            __syncthreads();
            // ChP[blk][b][u] = sum_{k<8} Hs[b][k] * Ws[k][u]  (bf16, parity buffer)
            {
                __bf16* CHPt = CHP + (size_t)(t & 1) * 2097152;
                int bh = tid >> 7;            // batch half
                int u0 = (tid & 127) * 4;     // 4 units per thread
                #pragma unroll 4
                for (int bb = 0; bb < 32; bb++) {
                    int b = bh * 32 + bb;
                    float4 hv0 = *(const float4*)&Hs[b][0];
                    float4 hv1 = *(const float4*)&Hs[b][4];
                    float a0 = 0.f, a1 = 0.f, a2 = 0.f, a3 = 0.f;
                    a0 += hv0.x * wreg[0][0]; a1 += hv0.x * wreg[0][1];
                    a2 += hv0.x * wreg[0][2]; a3 += hv0.x * wreg[0][3];
                    a0 += hv0.y * wreg[1][0]; a1 += hv0.y * wreg[1][1];
                    a2 += hv0.y * wreg[1][2]; a3 += hv0.y * wreg[1][3];
                    a0 += hv0.z * wreg[2][0]; a1 += hv0.z * wreg[2][1];
                    a2 += hv0.z * wreg[2][2]; a3 += hv0.z * wreg[2][3];
                    a0 += hv0.w * wreg[3][0]; a1 += hv0.w * wreg[3][1];
                    a2 += hv0.w * wreg[3][2]; a3 += hv0.w * wreg[3][3];
                    a0 += hv1.x * wreg[4][0]; a1 += hv1.x * wreg[4][1];
                    a2 += hv1.x * wreg[4][2]; a3 += hv1.x * wreg[4][3];
                    a0 += hv1.y * wreg[5][0]; a1 += hv1.y * wreg[5][1];
                    a2 += hv1.y * wreg[5][2]; a3 += hv1.y * wreg[5][3];
                    a0 += hv1.z * wreg[6][0]; a1 += hv1.z * wreg[6][1];
                    a2 += hv1.z * wreg[6][2]; a3 += hv1.z * wreg[6][3];
                    a0 += hv1.w * wreg[7][0]; a1 += hv1.w * wreg[7][1];
                    a2 += hv1.w * wreg[7][2]; a3 += hv1.w * wreg[7][3];
                    union { __bf16 h[4]; unsigned long long q; } pk;
                    pk.h[0] = (__bf16)a0; pk.h[1] = (__bf16)a1;
                    pk.h[2] = (__bf16)a2; pk.h[3] = (__bf16)a3;
                    stc_u64(CHPt + ((size_t)blk * 64 + b) * 512 + u0, pk.q);
                }
            }
        }
        garrive(FLA, blk, (unsigned)(t + 1));
        gwait_all(FLA, (unsigned)(t + 1));

        // ---- Phase BC (block = batch b = blk): attention + o-combine ----
        {
            int b = blk;
            const __bf16* hb = HS + (size_t)(t + 1) * 32768 + b * 512;
            const __bf16* CHPt = CHP + (size_t)(t & 1) * 2097152;
            // issue all long-latency loads as one batch (one MALL window)
            bf16x8 h8 = ldb8(hb + lane * 8);
            unsigned cv[64];
            {
                const __bf16* cp = CHPt + (size_t)b * 512 + tid * 2;
                #pragma unroll
                for (int p = 0; p < 64; p++)
                    cv[p] = ldc_u32(cp + (size_t)p * 32768);
            }
            asm volatile("" ::: "memory");
            // e[r] = attn_proj[b][r] . h
            for (int r = w; r < 49; r += 4) {
                bf16x8 ap8 = ldb8(APb + (size_t)(b * 49 + r) * 512 + lane * 8);
                float s = 0.f;
                #pragma unroll
                for (int u = 0; u < 8; u++) s += (float)ap8[u] * (float)h8[u];
                #pragma unroll
                for (int off = 32; off > 0; off >>= 1) s += __shfl_xor(s, off);
                if (lane == 0) esh[r] = s;
            }
            __syncthreads();
            if (tid < 64) {
                float v = (tid < 49) ? esh[tid] : -3.0e38f;
                float mx = v;
                #pragma unroll
                for (int off = 32; off > 0; off >>= 1) mx = fmaxf(mx, __shfl_xor(mx, off));
                float ex = (tid < 49) ? expf(v - mx) : 0.0f;
                float sm = ex;
                #pragma unroll
                for (int off = 32; off > 0; off >>= 1) sm += __shfl_xor(sm, off);
                if (tid < 49) ash[tid] = ex / sm;
            }
            // ChP sum while softmax settles (4-chain ILP)
            float oh0, oh1;
            {
                float s00 = 0.f, s01 = 0.f, s10 = 0.f, s11 = 0.f;
                float s20 = 0.f, s21 = 0.f, s30 = 0.f, s31 = 0.f;
                #pragma unroll
                for (int p = 0; p < 64; p += 4) {
                    union { unsigned u; __bf16 h[2]; } c0, c1, c2, c3;
                    c0.u = cv[p]; c1.u = cv[p + 1]; c2.u = cv[p + 2]; c3.u = cv[p + 3];
                    s00 += (float)c0.h[0]; s01 += (float)c0.h[1];
                    s10 += (float)c1.h[0]; s11 += (float)c1.h[1];
                    s20 += (float)c2.h[0]; s21 += (float)c2.h[1];
                    s30 += (float)c3.h[0]; s31 += (float)c3.h[1];
                }
                oh0 = (s00 + s10) + (s20 + s30);
                oh1 = (s01 + s11) + (s21 + s31);
            }
            __syncthreads();
            // a-part via LU: oa[u] = sum_r att[r] * LU[b][r][u]  (2-chain ILP)
            float oa0 = 0.f, oa1 = 0.f, ob0 = 0.f, ob1 = 0.f;
            {
                const __bf16* lu = LUb + (size_t)b * 49 * 512 + tid * 2;
                #pragma unroll 8
                for (int r = 0; r < 48; r += 2) {
                    float wt0 = ash[r], wt1 = ash[r + 1];
                    union { unsigned u; __bf16 h[2]; } c0, c1;
                    c0.u = *(const unsigned*)(lu + (size_t)r * 512);
                    c1.u = *(const unsigned*)(lu + (size_t)(r + 1) * 512);
                    oa0 += wt0 * (float)c0.h[0]; oa1 += wt0 * (float)c0.h[1];
                    ob0 += wt1 * (float)c1.h[0]; ob1 += wt1 * (float)c1.h[1];
                }
                float wt = ash[48];
                union { unsigned u; __bf16 h[2]; } c;
                c.u = *(const unsigned*)(lu + (size_t)48 * 512);
                oa0 += wt * (float)c.h[0]; oa1 += wt * (float)c.h[1];
                oa0 += ob0; oa1 += ob1;
            }
            int u = tid * 2;
            float o0v = tanhf(oh0 + oa0 + bu[u]);
            float o1v = tanhf(oh1 + oa1 + bu[u + 1]);
            union { __bf16 h[2]; unsigned v; } pk;
            pk.h[0] = (__bf16)o0v; pk.h[1] = (__bf16)o1v;
            stc_u32((unsigned*)(OS + (size_t)(t + 1) * 32768 + b * 512 + u), pk.v);
        }
        garrive(FLB, blk, (unsigned)(t + 1));
    }
}

// ---------------- vocab: logits = O @ Wv^T + b, 128x128 LDS-tiled MFMA ----------------
// B operand converted f32 -> bf16 during LDS staging (no WV buffer needed).
__global__ __launch_bounds__(256) void vocab_kernel(
    const __bf16* A, const float* Wv, const float* bv, float* out)
{
    __shared__ __bf16 As[128][72];
    __shared__ __bf16 Bs[128][72];
    int tid = threadIdx.x;
    int m0 = blockIdx.x * 128;   // 16 mblk
    int n0 = blockIdx.y * 128;   // 79 nblk
    int w = tid >> 6, lane = tid & 63, row16 = lane & 15, kg = lane >> 4;
    int mw = (w & 1) * 64, nw = (w >> 1) * 64;
    f32x4 acc[4][4] = {};
    for (int k0 = 0; k0 < 512; k0 += 64) {
        #pragma unroll
        for (int q = 0; q < 2; q++) {
            int c = q * 256 + tid;
            int r = c >> 2, col = (c & 3) * 16;
            bf16x8 v0 = ldb8(A + (size_t)(m0 + r) * 512 + k0 + col);
            bf16x8 v1 = ldb8(A + (size_t)(m0 + r) * 512 + k0 + col + 8);
            *(bf16x8*)&As[r][col] = v0;
            *(bf16x8*)&As[r][col + 8] = v1;
            bf16x8 u0, u1;
            int nrow = n0 + r;
            if (nrow < 10000) {
                const float* bp = Wv + (size_t)nrow * 512 + k0 + col;
                #pragma unroll
                for (int u = 0; u < 8; u++) {
                    u0[u] = (__bf16)bp[u];
                    u1[u] = (__bf16)bp[u + 8];
                }
            } else {
                u0 = (bf16x8)(__bf16)0.0f;
                u1 = (bf16x8)(__bf16)0.0f;
            }
            *(bf16x8*)&Bs[r][col] = u0;
            *(bf16x8*)&Bs[r][col + 8] = u1;
        }
        __syncthreads();
        #pragma unroll
        for (int kt = 0; kt < 2; kt++) {
            bf16x8 af[4], bfr[4];
            #pragma unroll
            for (int i = 0; i < 4; i++)
                af[i] = *(const bf16x8*)&As[mw + i * 16 + row16][kt * 32 + kg * 8];
            #pragma unroll
            for (int j = 0; j < 4; j++)
                bfr[j] = *(const bf16x8*)&Bs[nw + j * 16 + row16][kt * 32 + kg * 8];
            #pragma unroll
            for (int i = 0; i < 4; i++)
                #pragma unroll
                for (int j = 0; j < 4; j++)
                    acc[i][j] = mfma_bf16(af[i], bfr[j], acc[i][j]);
        }
        __syncthreads();
    }
    #pragma unroll
    for (int j = 0; j < 4; j++) {
        int n = n0 + nw + j * 16 + row16;
        if (n < 10000) {
            float bvn = bv[n];
            #pragma unroll
            for (int i = 0; i < 4; i++) {
                #pragma unroll
                for (int r = 0; r < 4; r++) {
                    int m = m0 + mw + i * 16 + kg * 4 + r;   // m = t*64 + b
                    int tt = m >> 6, b = m & 63;
                    out[(size_t)(b * 32 + tt) * 10000 + n] = acc[i][j][r] + bvn;
                }
            }
        }
    }
}

extern "C" void kernel_launch(void* const* d_in, const int* in_sizes, int n_in,
                              void* d_out, int out_size, void* d_ws, size_t ws_size,
                              hipStream_t stream) {
    (void)in_sizes; (void)n_in; (void)out_size; (void)ws_size;
    const float* localf  = (const float*)d_in[0];
    const float* globalf = (const float*)d_in[1];
    const float* qvec    = (const float*)d_in[2];
    const int*   answers = (const int*)d_in[3];
    const float* emb     = (const float*)d_in[4];
    const float* Wg2o    = (const float*)d_in[5];
    const float* bg2o    = (const float*)d_in[6];
    const float* Wh      = (const float*)d_in[7];
    const float* Wc      = (const float*)d_in[8];
    const float* Wih     = (const float*)d_in[9];
    const float* Whh     = (const float*)d_in[10];
    const float* bih     = (const float*)d_in[11];
    const float* bhh     = (const float*)d_in[12];
    const float* Wattn   = (const float*)d_in[13];
    const float* Wu      = (const float*)d_in[14];
    const float* bu      = (const float*)d_in[15];
    const float* Wvocab  = (const float*)d_in[16];
    const float* bvocab  = (const float*)d_in[17];
    float* out = (float*)d_out;

    char* ws = (char*)d_ws;
    __bf16* WG  = (__bf16*)(ws + 0);          // 2048*1280 bf16 (gate-perm [W_ih|W_hh])   5,242,880
    __bf16* WhT = (__bf16*)(ws + 5242880);    // 512*512 bf16 (Wu_h transposed)             524,288
    __bf16* Y   = (__bf16*)(ws + 5767168);    // 32*64*256 bf16                           1,048,576
    float*  BG  = (float*) (ws + 6815744);    // 2048 f32 (b_ih+b_hh perm)                    8,192
    __bf16* OS  = (__bf16*)(ws + 6823936);    // 33 slots * 64*512 bf16 (o; slot0=o0)     2,162,688
    __bf16* HS  = (__bf16*)(ws + 8986624);    // 33 slots * 64*512 bf16 (h; slot0=h0)     2,162,688
    float*  CF0 = (float*) (ws + 11149312);   // 64*512 f32 (c0)                            131,072
    __bf16* APb = (__bf16*)(ws + 11280384);   // 64*49*512 bf16 (attn_proj)               3,211,264
    __bf16* LUb = (__bf16*)(ws + 14491648);   // 64*49*512 bf16 (LF @ Wu_a^T)             3,211,264
    __bf16* CHP = (__bf16*)(ws + 17702912);   // 2 parity * 64blk*64b*512u bf16           8,388,608
    unsigned* FLA = (unsigned*)(ws + 26091520); // 64 u32 flags (phase A)                       256
    unsigned* FLB = (unsigned*)(ws + 26091776); // 64 u32 flags (phase BC)                      256
    // total: 26,092,032 B  (within r1-verified >=27.5MB workspace)

    hipMemsetAsync(FLA, 0, 512, stream);
    convert_kernel<<<dim3(1024, 1, 3), 256, 0, stream>>>(
        Wih, Whh, bih, bhh, Wu, emb, answers,
        WG, BG, WhT, Y);
    init_kernel<<<dim3(8, 4, 3), 256, 0, stream>>>(
        qvec, globalf, Wh, Wc, Wg2o, bg2o, HS, CF0, OS);
    attnproj_kernel<<<dim3(49, 8), 256, 0, stream>>>(localf, Wattn, 1024, APb);
    attnproj_kernel<<<dim3(49, 8), 256, 0, stream>>>(localf, Wu, 1536, LUb);
    loop_kernel<<<GRID_BLKS, 256, 0, stream>>>(
        Y, WG, BG, WhT, bu, APb, LUb, CF0, OS, HS, CHP, FLA, FLB);
    vocab_kernel<<<dim3(16, 79), 256, 0, stream>>>(OS + 32768, Wvocab, bvocab, out);
}

// Round 6
// 962.753 us; speedup vs baseline: 1.6891x; 1.1665x over previous
//
#include <hip/hip_runtime.h>

#define DI __device__ __forceinline__

typedef float f32x4 __attribute__((ext_vector_type(4)));
typedef __bf16 bf16x8 __attribute__((ext_vector_type(8)));
typedef __bf16 bf16x4 __attribute__((ext_vector_type(4)));

static DI f32x4 mfma_bf16(bf16x8 a, bf16x8 b, f32x4 c) {
    return __builtin_amdgcn_mfma_f32_16x16x32_bf16(a, b, c, 0, 0, 0);
}
static DI bf16x8 ldb8(const __bf16* p) { return *(const bf16x8*)p; }
static DI float sigf(float x) { return 1.0f / (1.0f + expf(-x)); }

// sc1 coherent (write-through to memory-side cache) stores; relaxed agent atomics.
static DI void stc_u32(void* p, unsigned v) {
    __hip_atomic_store((unsigned*)p, v, __ATOMIC_RELAXED, __HIP_MEMORY_SCOPE_AGENT);
}
static DI void stc_u64(void* p, unsigned long long v) {
    __hip_atomic_store((unsigned long long*)p, v, __ATOMIC_RELAXED, __HIP_MEMORY_SCOPE_AGENT);
}
static DI unsigned ldc_u32(const void* p) {
    return __hip_atomic_load((const unsigned*)p, __ATOMIC_RELAXED, __HIP_MEMORY_SCOPE_AGENT);
}

// B=64, T=32, R=49, LOCAL=1024, QVEC=512, EMB=256, HID=512, VOCAB=10000

// ---------------- RMW-free distributed flag barrier (split arrive/wait) ----------------
// Arrival: __syncthreads() drains this block's sc1 data stores (vmcnt(0)) so data
// is at the coherence point before the flag becomes visible; then ONE flag store.
// Wait: wave 0 polls all 64 flags, one per lane.
static DI void garrive(unsigned* F, int idx, unsigned tgt) {
    __syncthreads();
    if (threadIdx.x == 0)
        __hip_atomic_store(&F[idx], tgt, __ATOMIC_RELAXED, __HIP_MEMORY_SCOPE_AGENT);
}
static DI void gwait_all(unsigned* F, unsigned tgt) {
    if (threadIdx.x < 64) {
        for (;;) {
            unsigned f = __hip_atomic_load(&F[threadIdx.x], __ATOMIC_RELAXED,
                                           __HIP_MEMORY_SCOPE_AGENT);
            if (__all(f >= tgt)) break;
            __builtin_amdgcn_s_sleep(1);
        }
    }
    __syncthreads();
}

// ---------------- conversions + gathers (z-dispatched) ----------------
__global__ void convert_kernel(
    const float* Wih, const float* Whh,
    const float* bih, const float* bhh, const float* Wu,
    const float* emb, const int* answers,
    __bf16* WGo, float* biasg, __bf16* WhTo, __bf16* Yo)
{
    int z = blockIdx.z;
    int stride = gridDim.x * blockDim.x;
    int tid0 = blockIdx.x * blockDim.x + threadIdx.x;
    if (z == 0) {
        // Gate-permuted concat [W_ih | W_hh] -> WG [2048 perm rows, 1280]
        // perm row n <-> original row r = (n&3)*512 + (n>>2)  (unit-major)
        // div-free: block -> 2 rows, thread -> k stride
        #pragma unroll
        for (int rr = 0; rr < 2; rr++) {
            int n = blockIdx.x * 2 + rr;
            int r = (n & 3) * 512 + (n >> 2);
            const float* sih = Wih + (size_t)r * 768;
            const float* shh = Whh + (size_t)r * 512;
            __bf16* dst = WGo + (size_t)n * 1280;
            for (int k = threadIdx.x; k < 1280; k += 256)
                dst[k] = (__bf16)((k < 768) ? sih[k] : shh[k - 768]);
        }
        if (blockIdx.x < 8) {
            int n = blockIdx.x * 256 + threadIdx.x;
            int r = (n & 3) * 512 + (n >> 2);
            biasg[n] = bih[r] + bhh[r];
        }
    } else if (z == 1) {
        // Wu_hT [512 k][512 u] = Wu[u][1024 + k]  (h-part of W_u, transposed)
        const int N = 512 * 512;
        for (int i = tid0; i < N; i += stride) {
            int k = i >> 9, u = i & 511;
            WhTo[i] = (__bf16)Wu[(size_t)u * 1536 + 1024 + k];
        }
    } else {
        // y_seq gather: t=0 -> emb[1]; t>=1 -> emb[answers[b, t-1]]   [32,64,256]
        const int N = 32 * 64 * 256;
        for (int i = tid0; i < N; i += stride) {
            int t = i >> 14;
            int b = (i >> 8) & 63;
            int e = i & 255;
            int tok = (t == 0) ? 1 : answers[b * 32 + (t - 1)];
            Yo[i] = (__bf16)emb[tok * 256 + e];
        }
    }
}

// ---------------- init: h0 = q@Wh^T, c0 = q@Wc^T, o0 = g@Wg2o^T + b ----------------
__global__ void init_kernel(
    const float* q, const float* g,
    const float* Wh, const float* Wc, const float* Wg2o, const float* bg2o,
    __bf16* h0b, float* c0f, __bf16* o0b)
{
    int z = blockIdx.z;
    const float* A; const float* B; int K;
    if (z == 0)      { A = q; B = Wh;   K = 512; }
    else if (z == 1) { A = q; B = Wc;   K = 512; }
    else             { A = g; B = Wg2o; K = 2048; }
    int n0 = blockIdx.x * 64, m0 = blockIdx.y * 16;
    __shared__ float As[32][16];
    __shared__ float Bs[32][64];
    int tid = threadIdx.x;
    int n = tid & 63, tyq = tid >> 6;
    float acc[4] = {0.f, 0.f, 0.f, 0.f};
    for (int k0 = 0; k0 < K; k0 += 32) {
        {
            int idx = tid * 2, row = idx >> 5, kk = idx & 31;
            const float* ar = A + (m0 + row) * K + k0 + kk;
            As[kk][row] = ar[0];
            As[kk + 1][row] = ar[1];
        }
        {
            int row = tid >> 2, kk = (tid & 3) * 8;
            const float* br = B + (n0 + row) * K + k0 + kk;
            float4 v0 = *(const float4*)br;
            float4 v1 = *(const float4*)(br + 4);
            Bs[kk + 0][row] = v0.x; Bs[kk + 1][row] = v0.y;
            Bs[kk + 2][row] = v0.z; Bs[kk + 3][row] = v0.w;
            Bs[kk + 4][row] = v1.x; Bs[kk + 5][row] = v1.y;
            Bs[kk + 6][row] = v1.z; Bs[kk + 7][row] = v1.w;
        }
        __syncthreads();
        #pragma unroll
        for (int k = 0; k < 32; k++) {
            float4 a = *(const float4*)&As[k][tyq * 4];
            float b = Bs[k][n];
            acc[0] += a.x * b; acc[1] += a.y * b; acc[2] += a.z * b; acc[3] += a.w * b;
        }
        __syncthreads();
    }
    int ng = n0 + n;
    #pragma unroll
    for (int i = 0; i < 4; i++) {
        int m = m0 + tyq * 4 + i;
        float v = acc[i];
        if (z == 0)      { h0b[m * 512 + ng] = (__bf16)v; }
        else if (z == 1) { c0f[m * 512 + ng] = v; }
        else             { o0b[m * 512 + ng] = (__bf16)(v + bg2o[ng]); }
    }
}

// ------- proj: out[3136,512] = LF[3136,1024] @ B^T (B rows stride ldb), MFMA -------
// Used twice: AP = LF @ W_attn^T (ldb=1024), LU = LF @ Wu_a^T (ldb=1536, a-part cols).
__global__ __launch_bounds__(256) void attnproj_kernel(
    const float* Af, const float* Bf, int ldb, __bf16* APo)
{
    __shared__ __bf16 As[64][72];
    __shared__ __bf16 Bs[64][72];
    int tid = threadIdx.x;
    int m0 = blockIdx.x * 64, n0 = blockIdx.y * 64;
    int w = tid >> 6, lane = tid & 63, row16 = lane & 15, kg = lane >> 4;
    f32x4 acc[4] = {};
    for (int k0 = 0; k0 < 1024; k0 += 64) {
        int r = tid >> 2, col = (tid & 3) * 16;
        const float* ap = Af + (size_t)(m0 + r) * 1024 + k0 + col;
        const float* bp = Bf + (size_t)(n0 + r) * ldb + k0 + col;
        bf16x8 va0, va1, vb0, vb1;
        #pragma unroll
        for (int u = 0; u < 8; u++) {
            va0[u] = (__bf16)ap[u]; va1[u] = (__bf16)ap[u + 8];
            vb0[u] = (__bf16)bp[u]; vb1[u] = (__bf16)bp[u + 8];
        }
        *(bf16x8*)&As[r][col] = va0; *(bf16x8*)&As[r][col + 8] = va1;
        *(bf16x8*)&Bs[r][col] = vb0; *(bf16x8*)&Bs[r][col + 8] = vb1;
        __syncthreads();
        #pragma unroll
        for (int kt = 0; kt < 2; kt++) {
            bf16x8 af = *(const bf16x8*)&As[w * 16 + row16][kt * 32 + kg * 8];
            #pragma unroll
            for (int j = 0; j < 4; j++) {
                bf16x8 bfv = *(const bf16x8*)&Bs[j * 16 + row16][kt * 32 + kg * 8];
                acc[j] = mfma_bf16(af, bfv, acc[j]);
            }
        }
        __syncthreads();
    }
    #pragma unroll
    for (int j = 0; j < 4; j++)
        #pragma unroll
        for (int r = 0; r < 4; r++)
            APo[(size_t)(m0 + w * 16 + kg * 4 + r) * 512 + n0 + j * 16 + row16] =
                (__bf16)acc[j][r];
}

// ---------------- persistent step-loop kernel (grid = 128 blocks) ----------------
// Dedicated pipelines: blocks 0..63 = A (gates/LSTM/ChP for their 8-unit slice),
// blocks 64..127 = BC (attention + o-combine for their batch). seg-yh(t+1) on the
// A-CUs now runs CONCURRENTLY with BC(t) on the BC-CUs, removing it from the
// per-step critical chain. BC stages AP[b] + LU[b] to LDS once (100KB unused in
// the BC path). Flag protocol / slots / CHP parity identical to r5.
__global__ __launch_bounds__(256, 1) void loop_kernel(
    const __bf16* Yall, const __bf16* WG, const float* BG,
    const __bf16* WhT, const float* bu,
    const __bf16* APb, const __bf16* LUb, const float* CF0,
    __bf16* OS, __bf16* HS, __bf16* CHP, unsigned* FLA, unsigned* FLB)
{
    __shared__ float S[64][34];
    __shared__ float Cs[64][8];
    __shared__ float Hs[64][8];
    __shared__ __bf16 Ws[8][512];      // A: Wu_hT slice
    __shared__ __bf16 WGs[32 * 1280];  // A: WG slice (XOR-swizzled). BC: AP[b] stage.
    __shared__ __bf16 LUs[49 * 512];   // BC: LU[b] stage (50KB; unused by A)
    __shared__ float BGs[32];
    __shared__ float esh[64];
    __shared__ float ash[64];
    int tid = threadIdx.x;
    int blk = blockIdx.x;
    int w = tid >> 6, lane = tid & 63, row16 = lane & 15, kg4 = lane >> 4;

    if (blk < 64) {
        // ================= A pipeline (block = 8-unit slice) =================
        int n0 = blk * 32;
        // WG slice -> LDS, swizzled: 32 rows x 160 granules of 16B
        for (int i = tid; i < 32 * 160; i += 256) {
            int n = i / 160, g = i % 160;
            bf16x8 v = ldb8(WG + (size_t)(n0 + n) * 1280 + g * 8);
            *(bf16x8*)((char*)WGs + ((n * 2560 + g * 16) ^ ((n & 7) << 4))) = v;
        }
        for (int i = tid; i < 8 * 512; i += 256)
            Ws[i >> 9][i & 511] = WhT[(size_t)(blk * 8 + (i >> 9)) * 512 + (i & 511)];
        if (tid < 32) BGs[tid] = BG[n0 + tid];
        {
            int b = tid >> 2, u0 = (tid & 3) * 2;
            Cs[b][u0]     = CF0[b * 512 + blk * 8 + u0];
            Cs[b][u0 + 1] = CF0[b * 512 + blk * 8 + u0 + 1];
        }
        __syncthreads();
        // step-invariant Ws fragment for the ChP partial (4 units x 8 k per thread)
        float wreg[8][4];
        {
            int u0c = (tid & 127) * 4;
            #pragma unroll
            for (int k = 0; k < 8; k++)
                #pragma unroll
                for (int j = 0; j < 4; j++)
                    wreg[k][j] = (float)Ws[k][u0c + j];
        }

        for (int t = 0; t < 32; t++) {
            gwait_all(FLA, (unsigned)t);   // h(t) visible (t=0 trivial)
            int arow = w * 16 + row16;
            f32x4 acc[2] = {};
            // ---- seg-yh: overlaps BC(t-1) on the BC CUs ----
            {
                const __bf16* Yt = Yall + t * 16384;
                const __bf16* Hp = HS + t * 32768;
                bf16x8 a_h[16];
                #pragma unroll
                for (int kt = 0; kt < 16; kt++)
                    a_h[kt] = ldb8(Hp + arow * 512 + kt * 32 + kg4 * 8);
                asm volatile("" ::: "memory");   // pin preloads
                #pragma unroll
                for (int kt = 0; kt < 8; kt++) {
                    bf16x8 af = ldb8(Yt + arow * 256 + kt * 32 + kg4 * 8);
                    #pragma unroll
                    for (int nt = 0; nt < 2; nt++) {
                        int row = nt * 16 + row16;
                        bf16x8 bfv = *(const bf16x8*)((const char*)WGs +
                            ((row * 2560 + kt * 64 + kg4 * 16) ^ ((row & 7) << 4)));
                        acc[nt] = mfma_bf16(af, bfv, acc[nt]);
                    }
                }
                #pragma unroll
                for (int kt = 24; kt < 40; kt++) {
                    bf16x8 af = a_h[kt - 24];
                    #pragma unroll
                    for (int nt = 0; nt < 2; nt++) {
                        int row = nt * 16 + row16;
                        bf16x8 bfv = *(const bf16x8*)((const char*)WGs +
                            ((row * 2560 + kt * 64 + kg4 * 16) ^ ((row & 7) << 4)));
                        acc[nt] = mfma_bf16(af, bfv, acc[nt]);
                    }
                }
            }
            gwait_all(FLB, (unsigned)t);   // o(t) visible (t=0 trivial)
            // ---- seg-o + pointwise + ChP ----
            {
                const __bf16* Op = OS + t * 32768;
                bf16x8 a_o[16];
                #pragma unroll
                for (int kt = 0; kt < 16; kt++)
                    a_o[kt] = ldb8(Op + arow * 512 + kt * 32 + kg4 * 8);
                asm volatile("" ::: "memory");   // pin preloads
                #pragma unroll
                for (int kt = 8; kt < 24; kt++) {
                    bf16x8 af = a_o[kt - 8];
                    #pragma unroll
                    for (int nt = 0; nt < 2; nt++) {
                        int row = nt * 16 + row16;
                        bf16x8 bfv = *(const bf16x8*)((const char*)WGs +
                            ((row * 2560 + kt * 64 + kg4 * 16) ^ ((row & 7) << 4)));
                        acc[nt] = mfma_bf16(af, bfv, acc[nt]);
                    }
                }
                #pragma unroll
                for (int nt = 0; nt < 2; nt++)
                    #pragma unroll
                    for (int r = 0; r < 4; r++)
                        S[w * 16 + kg4 * 4 + r][nt * 16 + row16] = acc[nt][r];
                __syncthreads();
                {
                    int b = tid >> 2, u0 = (tid & 3) * 2;
                    float h2[2];
                    #pragma unroll
                    for (int uu = 0; uu < 2; uu++) {
                        int u = u0 + uu;
                        float gi = S[b][u * 4 + 0] + BGs[u * 4 + 0];
                        float gf = S[b][u * 4 + 1] + BGs[u * 4 + 1];
                        float gg = S[b][u * 4 + 2] + BGs[u * 4 + 2];
                        float go = S[b][u * 4 + 3] + BGs[u * 4 + 3];
                        float cp = Cs[b][u];
                        float cn = sigf(gf) * cp + sigf(gi) * tanhf(gg);
                        h2[uu] = sigf(go) * tanhf(cn);
                        Cs[b][u] = cn;
                    }
                    Hs[b][u0] = h2[0];
                    Hs[b][u0 + 1] = h2[1];
                    union { __bf16 h[2]; unsigned v; } pk;
                    pk.h[0] = (__bf16)h2[0]; pk.h[1] = (__bf16)h2[1];
                    stc_u32((unsigned*)(HS + (t + 1) * 32768 + b * 512 + blk * 8 + u0), pk.v);
                }
                __syncthreads();
                // ChP[blk][b][u] = sum_{k<8} Hs[b][k] * Ws[k][u]  (bf16, parity buffer)
                {
                    __bf16* CHPt = CHP + (size_t)(t & 1) * 2097152;
                    int bh = tid >> 7;
                    int u0 = (tid & 127) * 4;
                    #pragma unroll 4
                    for (int bb = 0; bb < 32; bb++) {
                        int b = bh * 32 + bb;
                        float4 hv0 = *(const float4*)&Hs[b][0];
                        float4 hv1 = *(const float4*)&Hs[b][4];
                        float a0 = 0.f, a1 = 0.f, a2 = 0.f, a3 = 0.f;
                        a0 += hv0.x * wreg[0][0]; a1 += hv0.x * wreg[0][1];
                        a2 += hv0.x * wreg[0][2]; a3 += hv0.x * wreg[0][3];
                        a0 += hv0.y * wreg[1][0]; a1 += hv0.y * wreg[1][1];
                        a2 += hv0.y * wreg[1][2]; a3 += hv0.y * wreg[1][3];
                        a0 += hv0.z * wreg[2][0]; a1 += hv0.z * wreg[2][1];
                        a2 += hv0.z * wreg[2][2]; a3 += hv0.z * wreg[2][3];
                        a0 += hv0.w * wreg[3][0]; a1 += hv0.w * wreg[3][1];
                        a2 += hv0.w * wreg[3][2]; a3 += hv0.w * wreg[3][3];
                        a0 += hv1.x * wreg[4][0]; a1 += hv1.x * wreg[4][1];
                        a2 += hv1.x * wreg[4][2]; a3 += hv1.x * wreg[4][3];
                        a0 += hv1.y * wreg[5][0]; a1 += hv1.y * wreg[5][1];
                        a2 += hv1.y * wreg[5][2]; a3 += hv1.y * wreg[5][3];
                        a0 += hv1.z * wreg[6][0]; a1 += hv1.z * wreg[6][1];
                        a2 += hv1.z * wreg[6][2]; a3 += hv1.z * wreg[6][3];
                        a0 += hv1.w * wreg[7][0]; a1 += hv1.w * wreg[7][1];
                        a2 += hv1.w * wreg[7][2]; a3 += hv1.w * wreg[7][3];
                        union { __bf16 h[4]; unsigned long long q; } pk;
                        pk.h[0] = (__bf16)a0; pk.h[1] = (__bf16)a1;
                        pk.h[2] = (__bf16)a2; pk.h[3] = (__bf16)a3;
                        stc_u64(CHPt + ((size_t)blk * 64 + b) * 512 + u0, pk.q);
                    }
                }
            }
            garrive(FLA, blk, (unsigned)(t + 1));
        }
    } else {
        // ================= BC pipeline (block = batch b) =================
        int b = blk - 64;
        // stage AP[b] (reusing WGs) and LU[b] to LDS (both static)
        __bf16* APs = WGs;
        {
            const bf16x8* src_ap = (const bf16x8*)(APb + (size_t)b * 49 * 512);
            const bf16x8* src_lu = (const bf16x8*)(LUb + (size_t)b * 49 * 512);
            for (int i = tid; i < 49 * 64; i += 256) {
                ((bf16x8*)APs)[i] = src_ap[i];
                ((bf16x8*)LUs)[i] = src_lu[i];
            }
        }
        __syncthreads();

        for (int t = 0; t < 32; t++) {
            gwait_all(FLA, (unsigned)(t + 1));   // h(t+1), CHP(t+1) visible
            const __bf16* hb = HS + (size_t)(t + 1) * 32768 + b * 512;
            const __bf16* CHPt = CHP + (size_t)(t & 1) * 2097152;
            // issue all long-latency loads as one batch (one MALL window)
            bf16x8 h8 = ldb8(hb + lane * 8);
            unsigned cv[64];
            {
                const __bf16* cp = CHPt + (size_t)b * 512 + tid * 2;
                #pragma unroll
                for (int p = 0; p < 64; p++)
                    cv[p] = ldc_u32(cp + (size_t)p * 32768);
            }
            asm volatile("" ::: "memory");
            // e[r] = attn_proj[b][r] . h   (AP from LDS)
            for (int r = w; r < 49; r += 4) {
                bf16x8 ap8 = *(const bf16x8*)&APs[r * 512 + lane * 8];
                float s = 0.f;
                #pragma unroll
                for (int u = 0; u < 8; u++) s += (float)ap8[u] * (float)h8[u];
                #pragma unroll
                for (int off = 32; off > 0; off >>= 1) s += __shfl_xor(s, off);
                if (lane == 0) esh[r] = s;
            }
            __syncthreads();
            if (tid < 64) {
                float v = (tid < 49) ? esh[tid] : -3.0e38f;
                float mx = v;
                #pragma unroll
                for (int off = 32; off > 0; off >>= 1) mx = fmaxf(mx, __shfl_xor(mx, off));
                float ex = (tid < 49) ? expf(v - mx) : 0.0f;
                float sm = ex;
                #pragma unroll
                for (int off = 32; off > 0; off >>= 1) sm += __shfl_xor(sm, off);
                if (tid < 49) ash[tid] = ex / sm;
            }
            // ChP sum while softmax settles (4-chain ILP)
            float oh0, oh1;
            {
                float s00 = 0.f, s01 = 0.f, s10 = 0.f, s11 = 0.f;
                float s20 = 0.f, s21 = 0.f, s30 = 0.f, s31 = 0.f;
                #pragma unroll
                for (int p = 0; p < 64; p += 4) {
                    union { unsigned u; __bf16 h[2]; } c0, c1, c2, c3;
                    c0.u = cv[p]; c1.u = cv[p + 1]; c2.u = cv[p + 2]; c3.u = cv[p + 3];
                    s00 += (float)c0.h[0]; s01 += (float)c0.h[1];
                    s10 += (float)c1.h[0]; s11 += (float)c1.h[1];
                    s20 += (float)c2.h[0]; s21 += (float)c2.h[1];
                    s30 += (float)c3.h[0]; s31 += (float)c3.h[1];
                }
                oh0 = (s00 + s10) + (s20 + s30);
                oh1 = (s01 + s11) + (s21 + s31);
            }
            __syncthreads();
            // a-part via LU (LDS): oa[u] = sum_r att[r] * LU[b][r][u]  (2-chain ILP)
            float oa0 = 0.f, oa1 = 0.f, ob0 = 0.f, ob1 = 0.f;
            {
                const __bf16* lu = LUs + tid * 2;
                #pragma unroll 8
                for (int r = 0; r < 48; r += 2) {
                    float wt0 = ash[r], wt1 = ash[r + 1];
                    union { unsigned u; __bf16 h[2]; } c0, c1;
                    c0.u = *(const unsigned*)(lu + r * 512);
                    c1.u = *(const unsigned*)(lu + (r + 1) * 512);
                    oa0 += wt0 * (float)c0.h[0]; oa1 += wt0 * (float)c0.h[1];
                    ob0 += wt1 * (float)c1.h[0]; ob1 += wt1 * (float)c1.h[1];
                }
                float wt = ash[48];
                union { unsigned u; __bf16 h[2]; } c;
                c.u = *(const unsigned*)(lu + 48 * 512);
                oa0 += wt * (float)c.h[0]; oa1 += wt * (float)c.h[1];
                oa0 += ob0; oa1 += ob1;
            }
            int u = tid * 2;
            float o0v = tanhf(oh0 + oa0 + bu[u]);
            float o1v = tanhf(oh1 + oa1 + bu[u + 1]);
            union { __bf16 h[2]; unsigned v; } pk;
            pk.h[0] = (__bf16)o0v; pk.h[1] = (__bf16)o1v;
            stc_u32((unsigned*)(OS + (size_t)(t + 1) * 32768 + b * 512 + u), pk.v);
            garrive(FLB, b, (unsigned)(t + 1));
        }
    }
}

// ---------------- vocab: logits = O @ Wv^T + b ----------------
// grid (79 n-tiles, 2 m-groups). Full-K Wv tile (128 x 512) converted f32->bf16
// and staged ONCE in LDS -> Wv read 2x total (was 16x). Per m-subtile of 128,
// As staged per k-chunk; 4 waves x (64m x 64n) x acc[4][4].
__global__ __launch_bounds__(256) void vocab_kernel(
    const __bf16* A, const float* Wv, const float* bv, float* out)
{
    __shared__ __bf16 Bs[128][520];   // full-K B tile (pad: row stride 1040B)
    __shared__ __bf16 As[128][72];
    int tid = threadIdx.x;
    int n0 = blockIdx.x * 128;
    int m00 = blockIdx.y * 1024;
    int w = tid >> 6, lane = tid & 63, row16 = lane & 15, kg = lane >> 4;
    int mw = (w & 1) * 64, nw = (w >> 1) * 64;
    // stage full-K Wv tile once (2 threads per row, 256 cols each)
    {
        int r = tid >> 1, half = tid & 1;
        int nrow = n0 + r;
        int c0 = half * 256;
        if (nrow < 10000) {
            const float* bp = Wv + (size_t)nrow * 512 + c0;
            for (int c = 0; c < 256; c += 8) {
                bf16x8 v;
                #pragma unroll
                for (int u = 0; u < 8; u++) v[u] = (__bf16)bp[c + u];
                *(bf16x8*)&Bs[r][c0 + c] = v;
            }
        } else {
            bf16x8 z = (bf16x8)(__bf16)0.0f;
            for (int c = 0; c < 256; c += 8) *(bf16x8*)&Bs[r][c0 + c] = z;
        }
    }
    __syncthreads();
    for (int mt = 0; mt < 8; mt++) {
        int m0 = m00 + mt * 128;
        f32x4 acc[4][4] = {};
        for (int k0 = 0; k0 < 512; k0 += 64) {
            // stage As: 128 rows x 64 cols bf16
            #pragma unroll
            for (int q = 0; q < 4; q++) {
                int idx = q * 256 + tid;          // 0..1023
                int r = idx >> 3, col = (idx & 7) * 8;
                *(bf16x8*)&As[r][col] = ldb8(A + (size_t)(m0 + r) * 512 + k0 + col);
            }
            __syncthreads();
            #pragma unroll
            for (int kt = 0; kt < 2; kt++) {
                bf16x8 af[4], bfr[4];
                #pragma unroll
                for (int i = 0; i < 4; i++)
                    af[i] = *(const bf16x8*)&As[mw + i * 16 + row16][kt * 32 + kg * 8];
                #pragma unroll
                for (int j = 0; j < 4; j++)
                    bfr[j] = *(const bf16x8*)&Bs[nw + j * 16 + row16][k0 + kt * 32 + kg * 8];
                #pragma unroll
                for (int i = 0; i < 4; i++)
                    #pragma unroll
                    for (int j = 0; j < 4; j++)
                        acc[i][j] = mfma_bf16(af[i], bfr[j], acc[i][j]);
            }
            __syncthreads();
        }
        #pragma unroll
        for (int j = 0; j < 4; j++) {
            int n = n0 + nw + j * 16 + row16;
            if (n < 10000) {
                float bvn = bv[n];
                #pragma unroll
                for (int i = 0; i < 4; i++) {
                    #pragma unroll
                    for (int r = 0; r < 4; r++) {
                        int m = m0 + mw + i * 16 + kg * 4 + r;   // m = t*64 + b
                        int tt = m >> 6, b = m & 63;
                        out[(size_t)(b * 32 + tt) * 10000 + n] = acc[i][j][r] + bvn;
                    }
                }
            }
        }
    }
}

extern "C" void kernel_launch(void* const* d_in, const int* in_sizes, int n_in,
                              void* d_out, int out_size, void* d_ws, size_t ws_size,
                              hipStream_t stream) {
    (void)in_sizes; (void)n_in; (void)out_size; (void)ws_size;
    const float* localf  = (const float*)d_in[0];
    const float* globalf = (const float*)d_in[1];
    const float* qvec    = (const float*)d_in[2];
    const int*   answers = (const int*)d_in[3];
    const float* emb     = (const float*)d_in[4];
    const float* Wg2o    = (const float*)d_in[5];
    const float* bg2o    = (const float*)d_in[6];
    const float* Wh      = (const float*)d_in[7];
    const float* Wc      = (const float*)d_in[8];
    const float* Wih     = (const float*)d_in[9];
    const float* Whh     = (const float*)d_in[10];
    const float* bih     = (const float*)d_in[11];
    const float* bhh     = (const float*)d_in[12];
    const float* Wattn   = (const float*)d_in[13];
    const float* Wu      = (const float*)d_in[14];
    const float* bu      = (const float*)d_in[15];
    const float* Wvocab  = (const float*)d_in[16];
    const float* bvocab  = (const float*)d_in[17];
    float* out = (float*)d_out;

    char* ws = (char*)d_ws;
    __bf16* WG  = (__bf16*)(ws + 0);          // 2048*1280 bf16 (gate-perm [W_ih|W_hh])   5,242,880
    __bf16* WhT = (__bf16*)(ws + 5242880);    // 512*512 bf16 (Wu_h transposed)             524,288
    __bf16* Y   = (__bf16*)(ws + 5767168);    // 32*64*256 bf16                           1,048,576
    float*  BG  = (float*) (ws + 6815744);    // 2048 f32 (b_ih+b_hh perm)                    8,192
    __bf16* OS  = (__bf16*)(ws + 6823936);    // 33 slots * 64*512 bf16 (o; slot0=o0)     2,162,688
    __bf16* HS  = (__bf16*)(ws + 8986624);    // 33 slots * 64*512 bf16 (h; slot0=h0)     2,162,688
    float*  CF0 = (float*) (ws + 11149312);   // 64*512 f32 (c0)                            131,072
    __bf16* APb = (__bf16*)(ws + 11280384);   // 64*49*512 bf16 (attn_proj)               3,211,264
    __bf16* LUb = (__bf16*)(ws + 14491648);   // 64*49*512 bf16 (LF @ Wu_a^T)             3,211,264
    __bf16* CHP = (__bf16*)(ws + 17702912);   // 2 parity * 64blk*64b*512u bf16           8,388,608
    unsigned* FLA = (unsigned*)(ws + 26091520); // 64 u32 flags (phase A)                       256
    unsigned* FLB = (unsigned*)(ws + 26091776); // 64 u32 flags (phase BC)                      256
    // total: 26,092,032 B  (within r1-verified >=27.5MB workspace)

    hipMemsetAsync(FLA, 0, 512, stream);
    convert_kernel<<<dim3(1024, 1, 3), 256, 0, stream>>>(
        Wih, Whh, bih, bhh, Wu, emb, answers,
        WG, BG, WhT, Y);
    init_kernel<<<dim3(8, 4, 3), 256, 0, stream>>>(
        qvec, globalf, Wh, Wc, Wg2o, bg2o, HS, CF0, OS);
    attnproj_kernel<<<dim3(49, 8), 256, 0, stream>>>(localf, Wattn, 1024, APb);
    attnproj_kernel<<<dim3(49, 8), 256, 0, stream>>>(localf, Wu, 1536, LUb);
    loop_kernel<<<128, 256, 0, stream>>>(
        Y, WG, BG, WhT, bu, APb, LUb, CF0, OS, HS, CHP, FLA, FLB);
    vocab_kernel<<<dim3(79, 2), 256, 0, stream>>>(OS + 32768, Wvocab, bvocab, out);
}